// Round 14
// baseline (508.725 us; speedup 1.0000x reference)
//
#include <hip/hip_runtime.h>
#include <hip/hip_bf16.h>
#include <math.h>

typedef __attribute__((ext_vector_type(8))) __bf16 bf16x8;
typedef __attribute__((ext_vector_type(4))) float f32x4;
typedef __attribute__((ext_vector_type(4))) int i32x4;

// ---- sort configuration ---------------------------------------------------
#define NBUCKET 4096           // 16^3 regions of 8^3 cells; region = 9^3 rows
#define HB      256            // histogram blocks
// workspace layout (bytes)
#define WS_WP   0UL                    // packed weights     32 KB
#define WS_MAT  32768UL                // [HB][NBUCKET] u32   4 MB
#define WS_TOT  4227072UL              // 4096 u32
#define WS_BB   4243456UL              // 4096 u32
#define WS_REC  4259840UL              // rec[N] 32 B        64 MB
#define WS_NEED 71368704UL

// main-kernel LDS layout (bytes)
#define REG_OFF 0                      // bf16 region: 729 rows x 64 B
#define WGT_OFF 46656                  // 32 weight frags, 32 KB
#define BIA_OFF 79424                  // bias tables, 1152 B
#define LDS_TOT 80576                  // 2 blocks/CU

// ---------------------------------------------------------------------------
// Pack MLP weights into MFMA A-fragment layout (weights-as-A).
//   frags 0-7: wd1 ident | 8-11: wd2 K-perm | 12-27: wc1 F-layout | 28-31: wc2
// K-perm row(kt,kg,j) = 32kt + 16(j>>2) + 4kg + (j&3): previous layer's
// D-layout is directly the next B-fragment (zero cross-lane movement).
// ---------------------------------------------------------------------------
__global__ void pack_weights(const float* __restrict__ wd1,
                             const float* __restrict__ wd2,
                             const float* __restrict__ wc1,
                             const float* __restrict__ wc2,
                             __bf16* __restrict__ wp)
{
    int t0 = threadIdx.x;
    for (int it = 0; it < 8; ++it) {
        int t = it * 256 + t0;
        int frag = t >> 6;
        int lane = t & 63;
        int kg = lane >> 4;
        int c  = lane & 15;
        for (int j = 0; j < 8; ++j) {
            float v;
            if (frag < 8) {
                int k = kg * 8 + j;
                v = wd1[k * 128 + frag * 16 + c];
            } else if (frag < 12) {
                int kt = frag - 8;
                int row = 32 * kt + 16 * (j >> 2) + 4 * kg + (j & 3);
                v = wd2[row * 16 + c];
            } else if (frag < 28) {
                int f = frag - 12;
                int f3 = f >> 1, kt3 = f & 1;
                int row;
                if (kt3 == 0) row = (j < 4) ? (4 * kg + j) : (16 + 4 * kg + (j - 4));
                else          row = 32 + 8 * kg + j;
                v = (row < 43) ? wc1[row * 128 + f3 * 16 + c] : 0.0f;
            } else {
                int kt = frag - 28;
                int row = 32 * kt + 16 * (j >> 2) + 4 * kg + (j & 3);
                v = (c < 3) ? wc2[row * 3 + c] : 0.0f;
            }
            wp[frag * 512 + lane * 8 + j] = (__bf16)v;
        }
    }
}

__device__ __forceinline__ int bucket_key(float x, float y, float z) {
    int ix = (int)(x * 127.0f); ix = ix < 0 ? 0 : (ix > 127 ? 127 : ix);
    int iy = (int)(y * 127.0f); iy = iy < 0 ? 0 : (iy > 127 ? 127 : iy);
    int iz = (int)(z * 127.0f); iz = iz < 0 ? 0 : (iz > 127 ? 127 : iz);
    return ((ix >> 3) << 8) | ((iy >> 3) << 4) | (iz >> 3);
}

__global__ __launch_bounds__(256) void hist_lds(const float* __restrict__ coords,
                                                unsigned int* __restrict__ mat,
                                                int ppb)
{
    __shared__ unsigned int lh[NBUCKET];
    for (int i = threadIdx.x; i < NBUCKET; i += 256) lh[i] = 0u;
    __syncthreads();
    int base = blockIdx.x * ppb;
    for (int k = threadIdx.x; k < ppb; k += 256) {
        size_t b = 3 * (size_t)(base + k);
        atomicAdd(&lh[bucket_key(coords[b], coords[b + 1], coords[b + 2])], 1u);
    }
    __syncthreads();
    unsigned int* row = mat + (size_t)blockIdx.x * NBUCKET;
    for (int i = threadIdx.x; i < NBUCKET; i += 256) row[i] = lh[i];
}

__global__ __launch_bounds__(256) void col_scan(unsigned int* __restrict__ mat,
                                                unsigned int* __restrict__ total)
{
    int wid  = threadIdx.x >> 6;
    int lane = threadIdx.x & 63;
    int bkt  = blockIdx.x * 4 + wid;

    unsigned int v[4];
#pragma unroll
    for (int j = 0; j < 4; ++j)
        v[j] = mat[(size_t)(lane * 4 + j) * NBUCKET + bkt];
    unsigned int pre[4];
    unsigned int sum = 0;
#pragma unroll
    for (int j = 0; j < 4; ++j) { pre[j] = sum; sum += v[j]; }
    unsigned int inc = sum;
    for (int d = 1; d < 64; d <<= 1) {
        unsigned int u = __shfl_up(inc, d);
        if (lane >= d) inc += u;
    }
    unsigned int excl = inc - sum;
#pragma unroll
    for (int j = 0; j < 4; ++j)
        mat[(size_t)(lane * 4 + j) * NBUCKET + bkt] = excl + pre[j];
    if (lane == 63) total[bkt] = inc;
}

// exclusive scan of 4096 bucket totals (single block, 16 per thread).
__global__ __launch_bounds__(256) void bucket_scan(const unsigned int* __restrict__ total,
                                                   unsigned int* __restrict__ bbase)
{
    int t = threadIdx.x;
    unsigned int pre[16];
    unsigned int run = 0;
#pragma unroll
    for (int j = 0; j < 16; ++j) { pre[j] = run; run += total[t * 16 + j]; }
    unsigned int lane = t & 63;
    int wid = t >> 6;
    unsigned int inc = run;
    for (int d = 1; d < 64; d <<= 1) {
        unsigned int u = __shfl_up(inc, d);
        if (lane >= (unsigned)d) inc += u;
    }
    __shared__ unsigned int wt[4];
    if (lane == 63) wt[wid] = inc;
    __syncthreads();
    unsigned int wbase = 0;
    for (int w = 0; w < wid; ++w) wbase += wt[w];
    unsigned int excl = wbase + inc - run;
#pragma unroll
    for (int j = 0; j < 16; ++j) bbase[t * 16 + j] = excl + pre[j];
}

// scatter: packed 32-B records {x,y,z,dx, dy,dz,idx,0} in sorted order.
__global__ __launch_bounds__(256) void scatter_rec(const float* __restrict__ coords,
                                                   const float* __restrict__ rayd,
                                                   const unsigned int* __restrict__ mat,
                                                   const unsigned int* __restrict__ bbase,
                                                   float* __restrict__ rec,
                                                   int ppb)
{
    __shared__ unsigned int cur[NBUCKET];
    const unsigned int* row = mat + (size_t)blockIdx.x * NBUCKET;
    for (int i = threadIdx.x; i < NBUCKET; i += 256)
        cur[i] = bbase[i] + row[i];
    __syncthreads();
    int base = blockIdx.x * ppb;
    for (int k = threadIdx.x; k < ppb; k += 256) {
        int i = base + k;
        size_t b = 3 * (size_t)i;
        float x = coords[b], y = coords[b + 1], z = coords[b + 2];
        unsigned int dst = atomicAdd(&cur[bucket_key(x, y, z)], 1u);
        f32x4 r0 = {x, y, z, rayd[b]};
        f32x4 r1 = {rayd[b + 1], rayd[b + 2], __int_as_float(i), 0.0f};
        f32x4* rp = (f32x4*)rec + (size_t)dst * 2;
        rp[0] = r0;
        rp[1] = r1;
    }
}

__device__ __forceinline__ unsigned int pack2(float a, float b) {
    union { __bf16 h[2]; unsigned int u; } x;
    x.h[0] = (__bf16)a; x.h[1] = (__bf16)b;
    return x.u;
}

union BFU { bf16x8 v; unsigned int u[4]; };

// ---------------------------------------------------------------------------
// Bucket-resident NeRF forward: block b owns bucket b. Phase A stages the
// bucket's 9^3-row grid region into LDS as bf16 (fused f32->bf16 convert,
// XOR-swizzled 16-B granules). Phase B: all trilinear gathers are LDS reads;
// the only global traffic is the sequential record stream + output stores.
// MLP identical to r13 (weights-as-A, register-local layer handoffs).
// ---------------------------------------------------------------------------
__global__ __launch_bounds__(512)
void nerf_bucket(const float* __restrict__ grid,     // [128][128][128][32] f32
                 const float* __restrict__ rec,      // sorted 32-B records
                 const unsigned int* __restrict__ bbase,
                 const unsigned int* __restrict__ total,
                 const float* __restrict__ bd1,
                 const float* __restrict__ bd2,
                 const float* __restrict__ bc1,
                 const float* __restrict__ bc2,
                 const __bf16* __restrict__ wp,
                 float* __restrict__ out)            // [N][4]
{
    __shared__ __align__(16) char lds[LDS_TOT];
    float* ldsB1 = (float*)(lds + BIA_OFF);   // bd1[128]
    float* ldsB2 = ldsB1 + 128;               // bd2[16]
    float* ldsB3 = ldsB2 + 16;                // bc1[128]
    float* ldsB4 = ldsB3 + 128;               // bc2 padded[16]

    const int tid = threadIdx.x;
    const int bb  = blockIdx.x;               // bucket id
    const int bx  = (bb >> 8) & 15, by = (bb >> 4) & 15, bz = bb & 15;

    // ---- phase A: stage weights + biases + grid region ---------------------
    {
        const i32x4* src = (const i32x4*)wp;
        i32x4* dst = (i32x4*)(lds + WGT_OFF);
        for (int i = tid; i < 2048; i += 512) dst[i] = src[i];
        if (tid < 128) ldsB1[tid] = bd1[tid];
        if (tid < 16)  ldsB2[tid] = bd2[tid];
        if (tid < 128) ldsB3[tid] = bc1[tid];
        if (tid < 16)  ldsB4[tid] = (tid < 3) ? bc2[tid] : 0.0f;

        // region: 729 rows x 2 halves; row r holds grid row (8bx+dx, ...)
        for (int i = tid; i < 1458; i += 512) {
            int r = i >> 1, h = i & 1;
            int dx = r / 81, rem = r - dx * 81;
            int dy = rem / 9, dz = rem - dy * 9;
            int gx = 8 * bx + dx; gx = gx > 127 ? 127 : gx;
            int gy = 8 * by + dy; gy = gy > 127 ? 127 : gy;
            int gz = 8 * bz + dz; gz = gz > 127 ? 127 : gz;
            const f32x4* gp = (const f32x4*)(grid +
                (((size_t)gx << 14) + ((size_t)gy << 7) + gz) * 32 + h * 16);
            f32x4 a = gp[0], b = gp[1], c2 = gp[2], d = gp[3];
            BFU g0, g1;
            g0.u[0] = pack2(a[0], a[1]);  g0.u[1] = pack2(a[2], a[3]);
            g0.u[2] = pack2(b[0], b[1]);  g0.u[3] = pack2(b[2], b[3]);
            g1.u[0] = pack2(c2[0], c2[1]); g1.u[1] = pack2(c2[2], c2[3]);
            g1.u[2] = pack2(d[0], d[1]);  g1.u[3] = pack2(d[2], d[3]);
            int swz = (r & 3) << 4;
            char* rp = lds + REG_OFF + r * 64;
            *(bf16x8*)(rp + (((2 * h) * 16) ^ swz))     = g0.v;
            *(bf16x8*)(rp + (((2 * h + 1) * 16) ^ swz)) = g1.v;
        }
    }
    __syncthreads();

    const int lane = tid & 63;
    const int wid  = tid >> 6;             // 0..7
    const int c    = lane & 15;
    const int kg   = lane >> 4;
    const int lb   = lane * 16;
    const int rsub = (lane >> 4) & 1;

    const int s   = (int)bbase[bb];
    const int cnt = (int)total[bb];
    const int nchunk = (cnt + 127) >> 7;

    for (int q = 0; q < nchunk; ++q) {
        const int pbase = q * 128 + wid * 16;   // within-bucket base of wave
        // ---- load records (coalesced, clamped) ----------------------------
        int pidx = pbase + c;
        int pclamp = pidx < cnt ? pidx : cnt - 1;
        f32x4 recA = ((const f32x4*)rec)[((size_t)s + pclamp) * 2 + rsub];
        const bool valid = (pbase + c) < cnt;

        float px  = __shfl(recA[0], c) * 127.0f;
        float py  = __shfl(recA[1], c) * 127.0f;
        float pz  = __shfl(recA[2], c) * 127.0f;
        float dxv = __shfl(recA[3], c);
        float dyv = __shfl(recA[0], 16 + c);
        float dzv = __shfl(recA[1], 16 + c);
        int   pv  = __float_as_int(__shfl(recA[2], 16 + c));

        int ix = (int)floorf(px); ix = ix < 0 ? 0 : (ix > 126 ? 126 : ix);
        int iy = (int)floorf(py); iy = iy < 0 ? 0 : (iy > 126 ? 126 : iy);
        int iz = (int)floorf(pz); iz = iz < 0 ? 0 : (iz > 126 ? 126 : iz);
        float tx = px - (float)ix;
        float ty = py - (float)iy;
        float tz = pz - (float)iz;
        // local region row base (point is in this bucket by construction)
        int base_r = (ix - 8 * bx) * 81 + (iy - 8 * by) * 9 + (iz - 8 * bz);

        // ---- gather from LDS region (bf16, swizzled granules) -------------
        f32x4 fa = {0.0f, 0.0f, 0.0f, 0.0f};
        f32x4 fb = {0.0f, 0.0f, 0.0f, 0.0f};
        const int offs[8] = {0, 1, 9, 10, 81, 82, 90, 91};
#pragma unroll
        for (int cc = 0; cc < 8; ++cc) {
            int ddx = (cc >> 2) & 1, ddy = (cc >> 1) & 1, ddz = cc & 1;
            float w = (ddx ? tx : 1.0f - tx) *
                      (ddy ? ty : 1.0f - ty) *
                      (ddz ? tz : 1.0f - tz);
            int r = base_r + offs[cc];
            BFU g;
            g.v = *(const bf16x8*)(lds + REG_OFF + r * 64 +
                                   ((kg * 16) ^ ((r & 3) << 4)));
            float l0 = __uint_as_float(g.u[0] << 16);
            float h0 = __uint_as_float(g.u[0] & 0xffff0000u);
            float l1 = __uint_as_float(g.u[1] << 16);
            float h1 = __uint_as_float(g.u[1] & 0xffff0000u);
            float l2 = __uint_as_float(g.u[2] << 16);
            float h2 = __uint_as_float(g.u[2] & 0xffff0000u);
            float l3 = __uint_as_float(g.u[3] << 16);
            float h3 = __uint_as_float(g.u[3] & 0xffff0000u);
            fa[0] = fmaf(w, l0, fa[0]); fa[1] = fmaf(w, h0, fa[1]);
            fa[2] = fmaf(w, l1, fa[2]); fa[3] = fmaf(w, h1, fa[3]);
            fb[0] = fmaf(w, l2, fb[0]); fb[1] = fmaf(w, h2, fb[1]);
            fb[2] = fmaf(w, l3, fb[2]); fb[3] = fmaf(w, h3, fb[3]);
        }
        BFU b0;
        b0.u[0] = pack2(fa[0], fa[1]); b0.u[1] = pack2(fa[2], fa[3]);
        b0.u[2] = pack2(fb[0], fb[1]); b0.u[3] = pack2(fb[2], fb[3]);

        // ---- view embedding: 6 transcendentals + angle doubling -----------
        float s1x = __sinf(dxv), c1x = __cosf(dxv);
        float s1y = __sinf(dyv), c1y = __cosf(dyv);
        float s1z = __sinf(dzv), c1z = __cosf(dzv);
        float s2x = 2.0f * s1x * c1x, c2x = fmaf(-2.0f * s1x, s1x, 1.0f);
        float s2y = 2.0f * s1y * c1y, c2y = fmaf(-2.0f * s1y, s1y, 1.0f);
        float s2z = 2.0f * s1z * c1z, c2z = fmaf(-2.0f * s1z, s1z, 1.0f);
        float s4x = 2.0f * s2x * c2x, c4x = fmaf(-2.0f * s2x, s2x, 1.0f);
        float s4y = 2.0f * s2y * c2y, c4y = fmaf(-2.0f * s2y, s2y, 1.0f);
        float s4z = 2.0f * s2z * c2z, c4z = fmaf(-2.0f * s2z, s2z, 1.0f);
        float s8x = 2.0f * s4x * c4x, c8x = fmaf(-2.0f * s4x, s4x, 1.0f);
        float s8y = 2.0f * s4y * c4y, c8y = fmaf(-2.0f * s4y, s4y, 1.0f);
        float s8z = 2.0f * s4z * c4z, c8z = fmaf(-2.0f * s4z, s4z, 1.0f);

        float E0, E1, E2, E3, G0, G1, G2, G3, G4, G5, G6, G7;
        if (kg == 0) {
            E0 = dxv; E1 = dyv; E2 = dzv; E3 = s1x;
            G0 = c1y; G1 = c1z; G2 = c2x; G3 = c2y;
            G4 = c2z; G5 = c4x; G6 = c4y; G7 = c4z;
        } else if (kg == 1) {
            E0 = s1y; E1 = s1z; E2 = s2x; E3 = s2y;
            G0 = c8x; G1 = c8y; G2 = c8z;
            G3 = 0.0f; G4 = 0.0f; G5 = 0.0f; G6 = 0.0f; G7 = 0.0f;
        } else if (kg == 2) {
            E0 = s2z; E1 = s4x; E2 = s4y; E3 = s4z;
            G0 = G1 = G2 = G3 = G4 = G5 = G6 = G7 = 0.0f;
        } else {
            E0 = s8x; E1 = s8y; E2 = s8z; E3 = c1x;
            G0 = G1 = G2 = G3 = G4 = G5 = G6 = G7 = 0.0f;
        }

        // ---- L1 -------------------------------------------------------------
        f32x4 acc[8];
#pragma unroll
        for (int n = 0; n < 8; ++n) {
            f32x4 bi = *(const f32x4*)(ldsB1 + n * 16 + kg * 4);
            bf16x8 A = *(const bf16x8*)(lds + WGT_OFF + n * 1024 + lb);
            acc[n] = __builtin_amdgcn_mfma_f32_16x16x32_bf16(A, b0.v, bi, 0, 0, 0);
        }
        unsigned int pk[8][2];
#pragma unroll
        for (int n = 0; n < 8; ++n) {
            pk[n][0] = pack2(fmaxf(acc[n][0], 0.0f), fmaxf(acc[n][1], 0.0f));
            pk[n][1] = pack2(fmaxf(acc[n][2], 0.0f), fmaxf(acc[n][3], 0.0f));
        }

        // ---- L2 -------------------------------------------------------------
        f32x4 a2A = *(const f32x4*)(ldsB2 + kg * 4);
        f32x4 a2B = {0.0f, 0.0f, 0.0f, 0.0f};
#pragma unroll
        for (int kt = 0; kt < 4; ++kt) {
            BFU B;
            B.u[0] = pk[2 * kt][0];     B.u[1] = pk[2 * kt][1];
            B.u[2] = pk[2 * kt + 1][0]; B.u[3] = pk[2 * kt + 1][1];
            bf16x8 A = *(const bf16x8*)(lds + WGT_OFF + (8 + kt) * 1024 + lb);
            if (kt & 1) a2B = __builtin_amdgcn_mfma_f32_16x16x32_bf16(A, B.v, a2B, 0, 0, 0);
            else        a2A = __builtin_amdgcn_mfma_f32_16x16x32_bf16(A, B.v, a2A, 0, 0, 0);
        }
        f32x4 accd = a2A + a2B;
        float dens = fmaxf(accd[0], 0.0f);

        // ---- L3 -------------------------------------------------------------
        BFU Bk0, Bk1;
        Bk0.u[0] = pack2(accd[0], accd[1]);
        Bk0.u[1] = pack2(accd[2], accd[3]);
        Bk0.u[2] = pack2(E0, E1);
        Bk0.u[3] = pack2(E2, E3);
        Bk1.u[0] = pack2(G0, G1);
        Bk1.u[1] = pack2(G2, G3);
        Bk1.u[2] = pack2(G4, G5);
        Bk1.u[3] = pack2(G6, G7);

        f32x4 acc3[8];
#pragma unroll
        for (int n = 0; n < 8; ++n) {
            f32x4 bi = *(const f32x4*)(ldsB3 + n * 16 + kg * 4);
            bf16x8 w0 = *(const bf16x8*)(lds + WGT_OFF + (12 + n * 2 + 0) * 1024 + lb);
            bf16x8 w1 = *(const bf16x8*)(lds + WGT_OFF + (12 + n * 2 + 1) * 1024 + lb);
            acc3[n] = __builtin_amdgcn_mfma_f32_16x16x32_bf16(w0, Bk0.v, bi, 0, 0, 0);
            acc3[n] = __builtin_amdgcn_mfma_f32_16x16x32_bf16(w1, Bk1.v, acc3[n], 0, 0, 0);
        }
        unsigned int pk3[8][2];
#pragma unroll
        for (int n = 0; n < 8; ++n) {
            pk3[n][0] = pack2(fmaxf(acc3[n][0], 0.0f), fmaxf(acc3[n][1], 0.0f));
            pk3[n][1] = pack2(fmaxf(acc3[n][2], 0.0f), fmaxf(acc3[n][3], 0.0f));
        }

        // ---- L4 -------------------------------------------------------------
        f32x4 a4A = *(const f32x4*)(ldsB4 + kg * 4);
        f32x4 a4B = {0.0f, 0.0f, 0.0f, 0.0f};
#pragma unroll
        for (int kt = 0; kt < 4; ++kt) {
            BFU B;
            B.u[0] = pk3[2 * kt][0];     B.u[1] = pk3[2 * kt][1];
            B.u[2] = pk3[2 * kt + 1][0]; B.u[3] = pk3[2 * kt + 1][1];
            bf16x8 A = *(const bf16x8*)(lds + WGT_OFF + (28 + kt) * 1024 + lb);
            if (kt & 1) a4B = __builtin_amdgcn_mfma_f32_16x16x32_bf16(A, B.v, a4B, 0, 0, 0);
            else        a4A = __builtin_amdgcn_mfma_f32_16x16x32_bf16(A, B.v, a4A, 0, 0, 0);
        }
        f32x4 acco = a4A + a4B;

        // ---- store ----------------------------------------------------------
        if (lane < 16 && valid) {
            f32x4 o;
            o[0] = 1.0f / (1.0f + __expf(-acco[0]));
            o[1] = 1.0f / (1.0f + __expf(-acco[1]));
            o[2] = 1.0f / (1.0f + __expf(-acco[2]));
            o[3] = dens;
            ((f32x4*)out)[pv] = o;
        }
    }
}

// ---------------------------------------------------------------------------
// Fallback (no workspace): r13-style global-gather, unsorted.
// ---------------------------------------------------------------------------
__global__ __launch_bounds__(512)
void nerf_plain(const float* __restrict__ coords,
                const float* __restrict__ ray_d,
                const float* __restrict__ grid,
                const float* __restrict__ bd1,
                const float* __restrict__ bd2,
                const float* __restrict__ bc1,
                const float* __restrict__ bc2,
                const __bf16* __restrict__ wp,
                float* __restrict__ out,
                int ntiles)
{
    __shared__ __align__(16) char lds[32768 + 1152];
    float* ldsB1 = (float*)(lds + 32768);
    float* ldsB2 = ldsB1 + 128;
    float* ldsB3 = ldsB2 + 16;
    float* ldsB4 = ldsB3 + 128;

    const int tid = threadIdx.x;
    {
        const i32x4* src = (const i32x4*)wp;
        i32x4* dst = (i32x4*)lds;
        for (int i = tid; i < 2048; i += 512) dst[i] = src[i];
        if (tid < 128) ldsB1[tid] = bd1[tid];
        if (tid < 16)  ldsB2[tid] = bd2[tid];
        if (tid < 128) ldsB3[tid] = bc1[tid];
        if (tid < 16)  ldsB4[tid] = (tid < 3) ? bc2[tid] : 0.0f;
    }
    __syncthreads();

    const int lane = tid & 63;
    const int wid  = tid >> 6;
    const int c    = lane & 15;
    const int kg   = lane >> 4;
    const int lb   = lane * 16;

    for (int tile = blockIdx.x; tile < ntiles; tile += gridDim.x) {
        int pw = tile * 128 + wid * 16;
        float cval = (lane < 48) ? coords[(size_t)pw * 3 + lane] : 0.0f;
        float rval = (lane < 48) ? ray_d[(size_t)pw * 3 + lane] : 0.0f;
        float px  = __shfl(cval, 3 * c + 0) * 127.0f;
        float py  = __shfl(cval, 3 * c + 1) * 127.0f;
        float pz  = __shfl(cval, 3 * c + 2) * 127.0f;
        float dxv = __shfl(rval, 3 * c + 0);
        float dyv = __shfl(rval, 3 * c + 1);
        float dzv = __shfl(rval, 3 * c + 2);
        int pv = pw + c;

        int ix = (int)floorf(px); ix = ix < 0 ? 0 : (ix > 126 ? 126 : ix);
        int iy = (int)floorf(py); iy = iy < 0 ? 0 : (iy > 126 ? 126 : iy);
        int iz = (int)floorf(pz); iz = iz < 0 ? 0 : (iz > 126 ? 126 : iz);
        float tx = px - (float)ix;
        float ty = py - (float)iy;
        float tz = pz - (float)iz;

        f32x4 fa = {0.0f, 0.0f, 0.0f, 0.0f};
        f32x4 fb = {0.0f, 0.0f, 0.0f, 0.0f};
#pragma unroll
        for (int cc = 0; cc < 8; ++cc) {
            int ddx = (cc >> 2) & 1, ddy = (cc >> 1) & 1, ddz = cc & 1;
            float w = (ddx ? tx : 1.0f - tx) *
                      (ddy ? ty : 1.0f - ty) *
                      (ddz ? tz : 1.0f - tz);
            int idx = ((ix + ddx) << 14) + ((iy + ddy) << 7) + (iz + ddz);
            const f32x4* g = (const f32x4*)(grid + (size_t)idx * 32 + kg * 8);
            f32x4 v0 = g[0], v1 = g[1];
#pragma unroll
            for (int e = 0; e < 4; ++e) {
                fa[e] = fmaf(w, v0[e], fa[e]);
                fb[e] = fmaf(w, v1[e], fb[e]);
            }
        }
        BFU b0;
        b0.u[0] = pack2(fa[0], fa[1]); b0.u[1] = pack2(fa[2], fa[3]);
        b0.u[2] = pack2(fb[0], fb[1]); b0.u[3] = pack2(fb[2], fb[3]);

        float s1x = __sinf(dxv), c1x = __cosf(dxv);
        float s1y = __sinf(dyv), c1y = __cosf(dyv);
        float s1z = __sinf(dzv), c1z = __cosf(dzv);
        float s2x = 2.0f * s1x * c1x, c2x = fmaf(-2.0f * s1x, s1x, 1.0f);
        float s2y = 2.0f * s1y * c1y, c2y = fmaf(-2.0f * s1y, s1y, 1.0f);
        float s2z = 2.0f * s1z * c1z, c2z = fmaf(-2.0f * s1z, s1z, 1.0f);
        float s4x = 2.0f * s2x * c2x, c4x = fmaf(-2.0f * s2x, s2x, 1.0f);
        float s4y = 2.0f * s2y * c2y, c4y = fmaf(-2.0f * s2y, s2y, 1.0f);
        float s4z = 2.0f * s2z * c2z, c4z = fmaf(-2.0f * s2z, s2z, 1.0f);
        float s8x = 2.0f * s4x * c4x, c8x = fmaf(-2.0f * s4x, s4x, 1.0f);
        float s8y = 2.0f * s4y * c4y, c8y = fmaf(-2.0f * s4y, s4y, 1.0f);
        float s8z = 2.0f * s4z * c4z, c8z = fmaf(-2.0f * s4z, s4z, 1.0f);

        float E0, E1, E2, E3, G0, G1, G2, G3, G4, G5, G6, G7;
        if (kg == 0) {
            E0 = dxv; E1 = dyv; E2 = dzv; E3 = s1x;
            G0 = c1y; G1 = c1z; G2 = c2x; G3 = c2y;
            G4 = c2z; G5 = c4x; G6 = c4y; G7 = c4z;
        } else if (kg == 1) {
            E0 = s1y; E1 = s1z; E2 = s2x; E3 = s2y;
            G0 = c8x; G1 = c8y; G2 = c8z;
            G3 = 0.0f; G4 = 0.0f; G5 = 0.0f; G6 = 0.0f; G7 = 0.0f;
        } else if (kg == 2) {
            E0 = s2z; E1 = s4x; E2 = s4y; E3 = s4z;
            G0 = G1 = G2 = G3 = G4 = G5 = G6 = G7 = 0.0f;
        } else {
            E0 = s8x; E1 = s8y; E2 = s8z; E3 = c1x;
            G0 = G1 = G2 = G3 = G4 = G5 = G6 = G7 = 0.0f;
        }

        f32x4 acc[8];
#pragma unroll
        for (int n = 0; n < 8; ++n) {
            f32x4 bi = *(const f32x4*)(ldsB1 + n * 16 + kg * 4);
            bf16x8 A = *(const bf16x8*)(lds + n * 1024 + lb);
            acc[n] = __builtin_amdgcn_mfma_f32_16x16x32_bf16(A, b0.v, bi, 0, 0, 0);
        }
        unsigned int pk[8][2];
#pragma unroll
        for (int n = 0; n < 8; ++n) {
            pk[n][0] = pack2(fmaxf(acc[n][0], 0.0f), fmaxf(acc[n][1], 0.0f));
            pk[n][1] = pack2(fmaxf(acc[n][2], 0.0f), fmaxf(acc[n][3], 0.0f));
        }
        f32x4 a2A = *(const f32x4*)(ldsB2 + kg * 4);
        f32x4 a2B = {0.0f, 0.0f, 0.0f, 0.0f};
#pragma unroll
        for (int kt = 0; kt < 4; ++kt) {
            BFU B;
            B.u[0] = pk[2 * kt][0];     B.u[1] = pk[2 * kt][1];
            B.u[2] = pk[2 * kt + 1][0]; B.u[3] = pk[2 * kt + 1][1];
            bf16x8 A = *(const bf16x8*)(lds + (8 + kt) * 1024 + lb);
            if (kt & 1) a2B = __builtin_amdgcn_mfma_f32_16x16x32_bf16(A, B.v, a2B, 0, 0, 0);
            else        a2A = __builtin_amdgcn_mfma_f32_16x16x32_bf16(A, B.v, a2A, 0, 0, 0);
        }
        f32x4 accd = a2A + a2B;
        float dens = fmaxf(accd[0], 0.0f);

        BFU Bk0, Bk1;
        Bk0.u[0] = pack2(accd[0], accd[1]);
        Bk0.u[1] = pack2(accd[2], accd[3]);
        Bk0.u[2] = pack2(E0, E1);
        Bk0.u[3] = pack2(E2, E3);
        Bk1.u[0] = pack2(G0, G1);
        Bk1.u[1] = pack2(G2, G3);
        Bk1.u[2] = pack2(G4, G5);
        Bk1.u[3] = pack2(G6, G7);

        f32x4 acc3[8];
#pragma unroll
        for (int n = 0; n < 8; ++n) {
            f32x4 bi = *(const f32x4*)(ldsB3 + n * 16 + kg * 4);
            bf16x8 w0 = *(const bf16x8*)(lds + (12 + n * 2 + 0) * 1024 + lb);
            bf16x8 w1 = *(const bf16x8*)(lds + (12 + n * 2 + 1) * 1024 + lb);
            acc3[n] = __builtin_amdgcn_mfma_f32_16x16x32_bf16(w0, Bk0.v, bi, 0, 0, 0);
            acc3[n] = __builtin_amdgcn_mfma_f32_16x16x32_bf16(w1, Bk1.v, acc3[n], 0, 0, 0);
        }
        unsigned int pk3[8][2];
#pragma unroll
        for (int n = 0; n < 8; ++n) {
            pk3[n][0] = pack2(fmaxf(acc3[n][0], 0.0f), fmaxf(acc3[n][1], 0.0f));
            pk3[n][1] = pack2(fmaxf(acc3[n][2], 0.0f), fmaxf(acc3[n][3], 0.0f));
        }
        f32x4 a4A = *(const f32x4*)(ldsB4 + kg * 4);
        f32x4 a4B = {0.0f, 0.0f, 0.0f, 0.0f};
#pragma unroll
        for (int kt = 0; kt < 4; ++kt) {
            BFU B;
            B.u[0] = pk3[2 * kt][0];     B.u[1] = pk3[2 * kt][1];
            B.u[2] = pk3[2 * kt + 1][0]; B.u[3] = pk3[2 * kt + 1][1];
            bf16x8 A = *(const bf16x8*)(lds + (28 + kt) * 1024 + lb);
            if (kt & 1) a4B = __builtin_amdgcn_mfma_f32_16x16x32_bf16(A, B.v, a4B, 0, 0, 0);
            else        a4A = __builtin_amdgcn_mfma_f32_16x16x32_bf16(A, B.v, a4A, 0, 0, 0);
        }
        f32x4 acco = a4A + a4B;

        if (lane < 16) {
            f32x4 o;
            o[0] = 1.0f / (1.0f + __expf(-acco[0]));
            o[1] = 1.0f / (1.0f + __expf(-acco[1]));
            o[2] = 1.0f / (1.0f + __expf(-acco[2]));
            o[3] = dens;
            ((f32x4*)out)[pv] = o;
        }
    }
}

extern "C" void kernel_launch(void* const* d_in, const int* in_sizes, int n_in,
                              void* d_out, int out_size, void* d_ws, size_t ws_size,
                              hipStream_t stream) {
    const float* coords = (const float*)d_in[0];
    const float* ray_d  = (const float*)d_in[1];
    const float* grid   = (const float*)d_in[2];
    const float* wd1    = (const float*)d_in[3];
    const float* bd1    = (const float*)d_in[4];
    const float* wd2    = (const float*)d_in[5];
    const float* bd2    = (const float*)d_in[6];
    const float* wc1    = (const float*)d_in[7];
    const float* bc1    = (const float*)d_in[8];
    const float* wc2    = (const float*)d_in[9];
    const float* bc2    = (const float*)d_in[10];
    float* out = (float*)d_out;

    int N = in_sizes[0] / 3;

    char* ws = (char*)d_ws;
    __bf16* wp = (__bf16*)(ws + WS_WP);

    pack_weights<<<1, 256, 0, stream>>>(wd1, wd2, wc1, wc2, wp);

    if (ws_size >= WS_NEED && (N % HB) == 0) {
        unsigned int* mat   = (unsigned int*)(ws + WS_MAT);
        unsigned int* total = (unsigned int*)(ws + WS_TOT);
        unsigned int* bbase = (unsigned int*)(ws + WS_BB);
        float* rec = (float*)(ws + WS_REC);
        int ppb = N / HB;

        hist_lds<<<HB, 256, 0, stream>>>(coords, mat, ppb);
        col_scan<<<NBUCKET / 4, 256, 0, stream>>>(mat, total);
        bucket_scan<<<1, 256, 0, stream>>>(total, bbase);
        scatter_rec<<<HB, 256, 0, stream>>>(coords, ray_d, mat, bbase, rec, ppb);
        nerf_bucket<<<NBUCKET, 512, 0, stream>>>(grid, rec, bbase, total,
                                                 bd1, bd2, bc1, bc2, wp, out);
    } else {
        int ntiles = N >> 7;
        int blocks = ntiles < 2048 ? ntiles : 2048;
        nerf_plain<<<blocks, 512, 0, stream>>>(coords, ray_d, grid,
                                               bd1, bd2, bc1, bc2,
                                               wp, out, ntiles);
    }
}

// Round 15
// 369.587 us; speedup vs baseline: 1.3765x; 1.3765x over previous
//
#include <hip/hip_runtime.h>
#include <hip/hip_bf16.h>
#include <math.h>

typedef __attribute__((ext_vector_type(8))) __bf16 bf16x8;
typedef __attribute__((ext_vector_type(4))) float f32x4;
typedef __attribute__((ext_vector_type(4))) int i32x4;

// ---- sort configuration ---------------------------------------------------
#define NBUCKET 512            // 8x8x8 regions of 16^3 cells
#define HB      256            // histogram blocks
// workspace layout (bytes)
#define WS_WP   0UL                    // packed weights     32 KB
#define WS_MAT  32768UL                // [HB][NBUCKET] u32  512 KB
#define WS_TOT  557056UL               // 512 u32
#define WS_BB   559104UL               // 512 u32
#define WS_REC  561152UL               // rec[N] 32 B        64 MB
#define WS_R13  67670016UL             // r13 tier ends here
#define WS_GB   67670016UL             // bf16 grid          134 MB
#define WS_FULL 201887744UL            // full tier

// ---------------------------------------------------------------------------
// Pack MLP weights into MFMA A-fragment layout (weights-as-A).
//   frags 0-7: wd1 ident | 8-11: wd2 K-perm | 12-27: wc1 F-layout | 28-31: wc2
// K-perm row(kt,kg,j) = 32kt + 16(j>>2) + 4kg + (j&3): previous layer's
// D-layout is directly the next layer's B-fragment (zero cross-lane moves).
// ---------------------------------------------------------------------------
__global__ void pack_weights(const float* __restrict__ wd1,
                             const float* __restrict__ wd2,
                             const float* __restrict__ wc1,
                             const float* __restrict__ wc2,
                             __bf16* __restrict__ wp)
{
    int t = blockIdx.x * 256 + threadIdx.x;   // 8 blocks x 256 = 2048
    int frag = t >> 6;
    int lane = t & 63;
    int kg = lane >> 4;
    int c  = lane & 15;
    for (int j = 0; j < 8; ++j) {
        float v;
        if (frag < 8) {
            int k = kg * 8 + j;
            v = wd1[k * 128 + frag * 16 + c];
        } else if (frag < 12) {
            int kt = frag - 8;
            int row = 32 * kt + 16 * (j >> 2) + 4 * kg + (j & 3);
            v = wd2[row * 16 + c];
        } else if (frag < 28) {
            int f = frag - 12;
            int f3 = f >> 1, kt3 = f & 1;
            int row;
            if (kt3 == 0) row = (j < 4) ? (4 * kg + j) : (16 + 4 * kg + (j - 4));
            else          row = 32 + 8 * kg + j;
            v = (row < 43) ? wc1[row * 128 + f3 * 16 + c] : 0.0f;
        } else {
            int kt = frag - 28;
            int row = 32 * kt + 16 * (j >> 2) + 4 * kg + (j & 3);
            v = (c < 3) ? wc2[row * 3 + c] : 0.0f;
        }
        wp[frag * 512 + lane * 8 + j] = (__bf16)v;
    }
}

// fp32 grid -> bf16 grid in ws (L3-resident, halves gather bytes+regs).
__global__ __launch_bounds__(256) void grid_to_bf16(const float* __restrict__ g,
                                                    __bf16* __restrict__ gb,
                                                    int n8)
{
    int i = blockIdx.x * blockDim.x + threadIdx.x;
    if (i >= n8) return;
    const f32x4* p = (const f32x4*)g + 2 * (size_t)i;
    f32x4 a = p[0], b = p[1];
    bf16x8 o;
#pragma unroll
    for (int e = 0; e < 4; ++e) {
        o[e]     = (__bf16)a[e];
        o[4 + e] = (__bf16)b[e];
    }
    ((bf16x8*)gb)[i] = o;
}

__device__ __forceinline__ int bucket_key(float x, float y, float z) {
    int ix = (int)(x * 127.0f); ix = ix < 0 ? 0 : (ix > 127 ? 127 : ix);
    int iy = (int)(y * 127.0f); iy = iy < 0 ? 0 : (iy > 127 ? 127 : iy);
    int iz = (int)(z * 127.0f); iz = iz < 0 ? 0 : (iz > 127 ? 127 : iz);
    return ((ix >> 4) << 6) | ((iy >> 4) << 3) | (iz >> 4);
}

__global__ __launch_bounds__(256) void hist_lds(const float* __restrict__ coords,
                                                unsigned int* __restrict__ mat,
                                                int ppb)
{
    __shared__ unsigned int lh[NBUCKET];
    for (int i = threadIdx.x; i < NBUCKET; i += 256) lh[i] = 0u;
    __syncthreads();
    int base = blockIdx.x * ppb;
    for (int k = threadIdx.x; k < ppb; k += 256) {
        size_t b = 3 * (size_t)(base + k);
        atomicAdd(&lh[bucket_key(coords[b], coords[b + 1], coords[b + 2])], 1u);
    }
    __syncthreads();
    unsigned int* row = mat + (size_t)blockIdx.x * NBUCKET;
    for (int i = threadIdx.x; i < NBUCKET; i += 256) row[i] = lh[i];
}

__global__ __launch_bounds__(256) void col_scan(unsigned int* __restrict__ mat,
                                                unsigned int* __restrict__ total)
{
    int wid  = threadIdx.x >> 6;
    int lane = threadIdx.x & 63;
    int bkt  = blockIdx.x * 4 + wid;

    unsigned int v[4];
#pragma unroll
    for (int j = 0; j < 4; ++j)
        v[j] = mat[(size_t)(lane * 4 + j) * NBUCKET + bkt];
    unsigned int pre[4];
    unsigned int sum = 0;
#pragma unroll
    for (int j = 0; j < 4; ++j) { pre[j] = sum; sum += v[j]; }
    unsigned int inc = sum;
    for (int d = 1; d < 64; d <<= 1) {
        unsigned int u = __shfl_up(inc, d);
        if (lane >= d) inc += u;
    }
    unsigned int excl = inc - sum;
#pragma unroll
    for (int j = 0; j < 4; ++j)
        mat[(size_t)(lane * 4 + j) * NBUCKET + bkt] = excl + pre[j];
    if (lane == 63) total[bkt] = inc;
}

__global__ __launch_bounds__(256) void bucket_scan(const unsigned int* __restrict__ total,
                                                   unsigned int* __restrict__ bbase)
{
    int t = threadIdx.x;
    unsigned int v0 = total[2 * t], v1 = total[2 * t + 1];
    unsigned int run = v0 + v1;
    unsigned int lane = t & 63;
    int wid = t >> 6;
    unsigned int inc = run;
    for (int d = 1; d < 64; d <<= 1) {
        unsigned int u = __shfl_up(inc, d);
        if (lane >= (unsigned)d) inc += u;
    }
    __shared__ unsigned int wt[4];
    if (lane == 63) wt[wid] = inc;
    __syncthreads();
    unsigned int wbase = 0;
    for (int w = 0; w < wid; ++w) wbase += wt[w];
    unsigned int excl = wbase + inc - run;
    bbase[2 * t]     = excl;
    bbase[2 * t + 1] = excl + v0;
}

// scatter: packed 32-B records {x,y,z,dx, dy,dz,idx,0} in sorted order.
__global__ __launch_bounds__(256) void scatter_rec(const float* __restrict__ coords,
                                                   const float* __restrict__ rayd,
                                                   const unsigned int* __restrict__ mat,
                                                   const unsigned int* __restrict__ bbase,
                                                   float* __restrict__ rec,
                                                   int ppb)
{
    __shared__ unsigned int cur[NBUCKET];
    const unsigned int* row = mat + (size_t)blockIdx.x * NBUCKET;
    for (int i = threadIdx.x; i < NBUCKET; i += 256)
        cur[i] = bbase[i] + row[i];
    __syncthreads();
    int base = blockIdx.x * ppb;
    for (int k = threadIdx.x; k < ppb; k += 256) {
        int i = base + k;
        size_t b = 3 * (size_t)i;
        float x = coords[b], y = coords[b + 1], z = coords[b + 2];
        unsigned int dst = atomicAdd(&cur[bucket_key(x, y, z)], 1u);
        f32x4 r0 = {x, y, z, rayd[b]};
        f32x4 r1 = {rayd[b + 1], rayd[b + 2], __int_as_float(i), 0.0f};
        f32x4* rp = (f32x4*)rec + (size_t)dst * 2;
        rp[0] = r0;
        rp[1] = r1;
    }
}

__device__ __forceinline__ unsigned int pack2(float a, float b) {
    union { __bf16 h[2]; unsigned int u; } x;
    x.h[0] = (__bf16)a; x.h[1] = (__bf16)b;
    return x.u;
}

union BFU { bf16x8 v; unsigned int u[4]; };

// shared MLP body (L1->L4 given b0 frag + dirs), used by both kernels
#define NERF_MLP_BODY(LDSW)                                                     \
    float s1x = __sinf(dxv), c1x = __cosf(dxv);                                 \
    float s1y = __sinf(dyv), c1y = __cosf(dyv);                                 \
    float s1z = __sinf(dzv), c1z = __cosf(dzv);                                 \
    float s2x = 2.0f * s1x * c1x, c2x = fmaf(-2.0f * s1x, s1x, 1.0f);           \
    float s2y = 2.0f * s1y * c1y, c2y = fmaf(-2.0f * s1y, s1y, 1.0f);           \
    float s2z = 2.0f * s1z * c1z, c2z = fmaf(-2.0f * s1z, s1z, 1.0f);           \
    float s4x = 2.0f * s2x * c2x, c4x = fmaf(-2.0f * s2x, s2x, 1.0f);           \
    float s4y = 2.0f * s2y * c2y, c4y = fmaf(-2.0f * s2y, s2y, 1.0f);           \
    float s4z = 2.0f * s2z * c2z, c4z = fmaf(-2.0f * s2z, s2z, 1.0f);           \
    float s8x = 2.0f * s4x * c4x, c8x = fmaf(-2.0f * s4x, s4x, 1.0f);           \
    float s8y = 2.0f * s4y * c4y, c8y = fmaf(-2.0f * s4y, s4y, 1.0f);           \
    float s8z = 2.0f * s4z * c4z, c8z = fmaf(-2.0f * s4z, s4z, 1.0f);           \
    float E0, E1, E2, E3, G0, G1, G2, G3, G4, G5, G6, G7;                       \
    if (kg == 0) {                                                              \
        E0 = dxv; E1 = dyv; E2 = dzv; E3 = s1x;                                 \
        G0 = c1y; G1 = c1z; G2 = c2x; G3 = c2y;                                 \
        G4 = c2z; G5 = c4x; G6 = c4y; G7 = c4z;                                 \
    } else if (kg == 1) {                                                       \
        E0 = s1y; E1 = s1z; E2 = s2x; E3 = s2y;                                 \
        G0 = c8x; G1 = c8y; G2 = c8z;                                           \
        G3 = 0.0f; G4 = 0.0f; G5 = 0.0f; G6 = 0.0f; G7 = 0.0f;                  \
    } else if (kg == 2) {                                                       \
        E0 = s2z; E1 = s4x; E2 = s4y; E3 = s4z;                                 \
        G0 = G1 = G2 = G3 = G4 = G5 = G6 = G7 = 0.0f;                           \
    } else {                                                                    \
        E0 = s8x; E1 = s8y; E2 = s8z; E3 = c1x;                                 \
        G0 = G1 = G2 = G3 = G4 = G5 = G6 = G7 = 0.0f;                           \
    }                                                                           \
    f32x4 acc[8];                                                               \
    _Pragma("unroll")                                                           \
    for (int n = 0; n < 8; ++n) {                                               \
        f32x4 bi = *(const f32x4*)(ldsB1 + n * 16 + kg * 4);                    \
        bf16x8 A = *(const bf16x8*)(LDSW + n * 1024 + lb);                      \
        acc[n] = __builtin_amdgcn_mfma_f32_16x16x32_bf16(A, b0.v, bi, 0, 0, 0); \
    }                                                                           \
    unsigned int pk[8][2];                                                      \
    _Pragma("unroll")                                                           \
    for (int n = 0; n < 8; ++n) {                                               \
        pk[n][0] = pack2(fmaxf(acc[n][0], 0.0f), fmaxf(acc[n][1], 0.0f));       \
        pk[n][1] = pack2(fmaxf(acc[n][2], 0.0f), fmaxf(acc[n][3], 0.0f));       \
    }                                                                           \
    f32x4 a2A = *(const f32x4*)(ldsB2 + kg * 4);                                \
    f32x4 a2B = {0.0f, 0.0f, 0.0f, 0.0f};                                       \
    _Pragma("unroll")                                                           \
    for (int kt = 0; kt < 4; ++kt) {                                            \
        BFU B;                                                                  \
        B.u[0] = pk[2 * kt][0];     B.u[1] = pk[2 * kt][1];                     \
        B.u[2] = pk[2 * kt + 1][0]; B.u[3] = pk[2 * kt + 1][1];                 \
        bf16x8 A = *(const bf16x8*)(LDSW + (8 + kt) * 1024 + lb);               \
        if (kt & 1) a2B = __builtin_amdgcn_mfma_f32_16x16x32_bf16(A, B.v, a2B, 0, 0, 0); \
        else        a2A = __builtin_amdgcn_mfma_f32_16x16x32_bf16(A, B.v, a2A, 0, 0, 0); \
    }                                                                           \
    f32x4 accd = a2A + a2B;                                                     \
    float dens = fmaxf(accd[0], 0.0f);                                          \
    BFU Bk0, Bk1;                                                               \
    Bk0.u[0] = pack2(accd[0], accd[1]);                                         \
    Bk0.u[1] = pack2(accd[2], accd[3]);                                         \
    Bk0.u[2] = pack2(E0, E1);                                                   \
    Bk0.u[3] = pack2(E2, E3);                                                   \
    Bk1.u[0] = pack2(G0, G1);                                                   \
    Bk1.u[1] = pack2(G2, G3);                                                   \
    Bk1.u[2] = pack2(G4, G5);                                                   \
    Bk1.u[3] = pack2(G6, G7);                                                   \
    f32x4 acc3[8];                                                              \
    _Pragma("unroll")                                                           \
    for (int n = 0; n < 8; ++n) {                                               \
        f32x4 bi = *(const f32x4*)(ldsB3 + n * 16 + kg * 4);                    \
        bf16x8 w0 = *(const bf16x8*)(LDSW + (12 + n * 2 + 0) * 1024 + lb);      \
        bf16x8 w1 = *(const bf16x8*)(LDSW + (12 + n * 2 + 1) * 1024 + lb);      \
        acc3[n] = __builtin_amdgcn_mfma_f32_16x16x32_bf16(w0, Bk0.v, bi, 0, 0, 0);      \
        acc3[n] = __builtin_amdgcn_mfma_f32_16x16x32_bf16(w1, Bk1.v, acc3[n], 0, 0, 0); \
    }                                                                           \
    unsigned int pk3[8][2];                                                     \
    _Pragma("unroll")                                                           \
    for (int n = 0; n < 8; ++n) {                                               \
        pk3[n][0] = pack2(fmaxf(acc3[n][0], 0.0f), fmaxf(acc3[n][1], 0.0f));    \
        pk3[n][1] = pack2(fmaxf(acc3[n][2], 0.0f), fmaxf(acc3[n][3], 0.0f));    \
    }                                                                           \
    f32x4 a4A = *(const f32x4*)(ldsB4 + kg * 4);                                \
    f32x4 a4B = {0.0f, 0.0f, 0.0f, 0.0f};                                       \
    _Pragma("unroll")                                                           \
    for (int kt = 0; kt < 4; ++kt) {                                            \
        BFU B;                                                                  \
        B.u[0] = pk3[2 * kt][0];     B.u[1] = pk3[2 * kt][1];                   \
        B.u[2] = pk3[2 * kt + 1][0]; B.u[3] = pk3[2 * kt + 1][1];               \
        bf16x8 A = *(const bf16x8*)(LDSW + (28 + kt) * 1024 + lb);              \
        if (kt & 1) a4B = __builtin_amdgcn_mfma_f32_16x16x32_bf16(A, B.v, a4B, 0, 0, 0); \
        else        a4A = __builtin_amdgcn_mfma_f32_16x16x32_bf16(A, B.v, a4A, 0, 0, 0); \
    }                                                                           \
    f32x4 acco = a4A + a4B;

// ---------------------------------------------------------------------------
// Pipelined main kernel (full tier): bf16 grid; iteration t consumes corner
// slices loaded during t-1's MLP, then issues t+1's 8 x 16-B loads before
// entering its own MLP.  One coalesced 32-B record per point.
// ---------------------------------------------------------------------------
__global__ __launch_bounds__(512)
void nerf_pipe(const __bf16* __restrict__ gb,       // bf16 grid
               const float* __restrict__ rec,       // sorted 32-B records
               const float* __restrict__ bd1,
               const float* __restrict__ bd2,
               const float* __restrict__ bc1,
               const float* __restrict__ bc2,
               const __bf16* __restrict__ wp,
               float* __restrict__ out,
               int ntiles)                          // 128-point tiles
{
    __shared__ __align__(16) char lds[32768 + 1152];
    float* ldsB1 = (float*)(lds + 32768);
    float* ldsB2 = ldsB1 + 128;
    float* ldsB3 = ldsB2 + 16;
    float* ldsB4 = ldsB3 + 128;

    const int tid = threadIdx.x;
    {
        const i32x4* src = (const i32x4*)wp;
        i32x4* dst = (i32x4*)lds;
        for (int i = tid; i < 2048; i += 512) dst[i] = src[i];
        if (tid < 128) ldsB1[tid] = bd1[tid];
        if (tid < 16)  ldsB2[tid] = bd2[tid];
        if (tid < 128) ldsB3[tid] = bc1[tid];
        if (tid < 16)  ldsB4[tid] = (tid < 3) ? bc2[tid] : 0.0f;
    }
    __syncthreads();

    const int lane = tid & 63;
    const int wid  = tid >> 6;
    const int c    = lane & 15;
    const int kg   = lane >> 4;
    const int lb   = lane * 16;
    const int rsub = (lane >> 4) & 1;

    const int per = (ntiles + gridDim.x - 1) / gridDim.x;
    int sb = blockIdx.x;
    if ((gridDim.x & 7) == 0)
        sb = (blockIdx.x & 7) * (gridDim.x >> 3) + (blockIdx.x >> 3);

    // ---- prologue ----------------------------------------------------------
    int t0 = sb * per;       if (t0 >= ntiles) t0 = ntiles - 1;
    int t1 = sb * per + 1;   if (t1 >= ntiles) t1 = ntiles - 1;
    f32x4 recA = ((const f32x4*)rec)[(size_t)(t0 * 128 + wid * 16 + c) * 2 + rsub];
    f32x4 recB = ((const f32x4*)rec)[(size_t)(t1 * 128 + wid * 16 + c) * 2 + rsub];

    bf16x8 g0, g1, g2, g3, g4, g5, g6, g7;
    float txc, tyc, tzc;
    {   // prep iter 0 from recA
        float px = __shfl(recA[0], c) * 127.0f;
        float py = __shfl(recA[1], c) * 127.0f;
        float pz = __shfl(recA[2], c) * 127.0f;
        int ix = (int)floorf(px); ix = ix < 0 ? 0 : (ix > 126 ? 126 : ix);
        int iy = (int)floorf(py); iy = iy < 0 ? 0 : (iy > 126 ? 126 : iy);
        int iz = (int)floorf(pz); iz = iz < 0 ? 0 : (iz > 126 ? 126 : iz);
        txc = px - (float)ix; tyc = py - (float)iy; tzc = pz - (float)iz;
        const __bf16* gp = gb + ((((size_t)ix << 14) + ((size_t)iy << 7) + iz) * 32 + kg * 8);
        g0 = *(const bf16x8*)(gp);
        g1 = *(const bf16x8*)(gp + 32);
        g2 = *(const bf16x8*)(gp + 4096);
        g3 = *(const bf16x8*)(gp + 4128);
        g4 = *(const bf16x8*)(gp + 524288);
        g5 = *(const bf16x8*)(gp + 524320);
        g6 = *(const bf16x8*)(gp + 528384);
        g7 = *(const bf16x8*)(gp + 528416);
    }

    for (int it = 0; it < per; ++it) {
        const int tile = sb * per + it;
        if (tile >= ntiles) break;

        // ---- consume current corner slices -> b0 frag ----------------------
        f32x4 fa = {0.0f, 0.0f, 0.0f, 0.0f};
        f32x4 fb = {0.0f, 0.0f, 0.0f, 0.0f};
        {
            const bf16x8 garr[8] = {g0, g1, g2, g3, g4, g5, g6, g7};
#pragma unroll
            for (int cc = 0; cc < 8; ++cc) {
                int ddx = (cc >> 2) & 1, ddy = (cc >> 1) & 1, ddz = cc & 1;
                float w = (ddx ? txc : 1.0f - txc) *
                          (ddy ? tyc : 1.0f - tyc) *
                          (ddz ? tzc : 1.0f - tzc);
                BFU g; g.v = garr[(cc >> 1) | ((cc & 1) << 2)];
                // note: garr order is {dz-major pairs}; map cc(dx,dy,dz):
                // loaded order g0..g7 = (dx,dy,dz) = 000,001,010,011,100,101,110,111
                g.v = garr[cc];
                float l0 = __uint_as_float(g.u[0] << 16);
                float h0 = __uint_as_float(g.u[0] & 0xffff0000u);
                float l1 = __uint_as_float(g.u[1] << 16);
                float h1 = __uint_as_float(g.u[1] & 0xffff0000u);
                float l2 = __uint_as_float(g.u[2] << 16);
                float h2 = __uint_as_float(g.u[2] & 0xffff0000u);
                float l3 = __uint_as_float(g.u[3] << 16);
                float h3 = __uint_as_float(g.u[3] & 0xffff0000u);
                fa[0] = fmaf(w, l0, fa[0]); fa[1] = fmaf(w, h0, fa[1]);
                fa[2] = fmaf(w, l1, fa[2]); fa[3] = fmaf(w, h1, fa[3]);
                fb[0] = fmaf(w, l2, fb[0]); fb[1] = fmaf(w, h2, fb[1]);
                fb[2] = fmaf(w, l3, fb[2]); fb[3] = fmaf(w, h3, fb[3]);
            }
        }
        BFU b0;
        b0.u[0] = pack2(fa[0], fa[1]); b0.u[1] = pack2(fa[2], fa[3]);
        b0.u[2] = pack2(fb[0], fb[1]); b0.u[3] = pack2(fb[2], fb[3]);

        // ---- current dirs / output index from recA -------------------------
        float dxv = __shfl(recA[3], c);
        float dyv = __shfl(recA[0], 16 + c);
        float dzv = __shfl(recA[1], 16 + c);
        int   pv  = __float_as_int(__shfl(recA[2], 16 + c));

        // ---- prep NEXT iteration from recB: issue 8 corner loads -----------
        {
            float px = __shfl(recB[0], c) * 127.0f;
            float py = __shfl(recB[1], c) * 127.0f;
            float pz = __shfl(recB[2], c) * 127.0f;
            int ix = (int)floorf(px); ix = ix < 0 ? 0 : (ix > 126 ? 126 : ix);
            int iy = (int)floorf(py); iy = iy < 0 ? 0 : (iy > 126 ? 126 : iy);
            int iz = (int)floorf(pz); iz = iz < 0 ? 0 : (iz > 126 ? 126 : iz);
            txc = px - (float)ix; tyc = py - (float)iy; tzc = pz - (float)iz;
            const __bf16* gp = gb + ((((size_t)ix << 14) + ((size_t)iy << 7) + iz) * 32 + kg * 8);
            g0 = *(const bf16x8*)(gp);
            g1 = *(const bf16x8*)(gp + 32);
            g2 = *(const bf16x8*)(gp + 4096);
            g3 = *(const bf16x8*)(gp + 4128);
            g4 = *(const bf16x8*)(gp + 524288);
            g5 = *(const bf16x8*)(gp + 524320);
            g6 = *(const bf16x8*)(gp + 528384);
            g7 = *(const bf16x8*)(gp + 528416);
        }
        // rotate records: recA <- recB, load new recB (t+2)
        recA = recB;
        {
            int t2 = tile + 2; if (t2 >= ntiles) t2 = ntiles - 1;
            recB = ((const f32x4*)rec)[(size_t)(t2 * 128 + wid * 16 + c) * 2 + rsub];
        }

        // ---- MLP (loads above retire underneath) ---------------------------
        NERF_MLP_BODY(lds + 0)

        if (lane < 16) {
            f32x4 o;
            o[0] = 1.0f / (1.0f + __expf(-acco[0]));
            o[1] = 1.0f / (1.0f + __expf(-acco[1]));
            o[2] = 1.0f / (1.0f + __expf(-acco[2]));
            o[3] = dens;
            ((f32x4*)out)[pv] = o;
        }
    }
}

// ---------------------------------------------------------------------------
// r13 kernel (middle tier: sorted records, fp32 grid) + plain fallback.
// ---------------------------------------------------------------------------
template <bool SORTED>
__global__ __launch_bounds__(512)
void nerf_wave(const float* __restrict__ coords,
               const float* __restrict__ ray_d,
               const float* __restrict__ grid,
               const float* __restrict__ bd1,
               const float* __restrict__ bd2,
               const float* __restrict__ bc1,
               const float* __restrict__ bc2,
               const __bf16* __restrict__ wp,
               const float* __restrict__ rec,
               float* __restrict__ out,
               int ntiles)
{
    __shared__ __align__(16) char lds[32768 + 1152];
    float* ldsB1 = (float*)(lds + 32768);
    float* ldsB2 = ldsB1 + 128;
    float* ldsB3 = ldsB2 + 16;
    float* ldsB4 = ldsB3 + 128;

    const int tid = threadIdx.x;
    {
        const i32x4* src = (const i32x4*)wp;
        i32x4* dst = (i32x4*)lds;
        for (int i = tid; i < 2048; i += 512) dst[i] = src[i];
        if (tid < 128) ldsB1[tid] = bd1[tid];
        if (tid < 16)  ldsB2[tid] = bd2[tid];
        if (tid < 128) ldsB3[tid] = bc1[tid];
        if (tid < 16)  ldsB4[tid] = (tid < 3) ? bc2[tid] : 0.0f;
    }
    __syncthreads();

    const int lane = tid & 63;
    const int wid  = tid >> 6;
    const int c    = lane & 15;
    const int kg   = lane >> 4;
    const int lb   = lane * 16;
    const int rsub = (lane >> 4) & 1;

    const int per = (ntiles + gridDim.x - 1) / gridDim.x;
    int sb = blockIdx.x;
    if ((gridDim.x & 7) == 0)
        sb = (blockIdx.x & 7) * (gridDim.x >> 3) + (blockIdx.x >> 3);

    f32x4 recA = {0.0f, 0.0f, 0.0f, 0.0f};
    if constexpr (SORTED) {
        int t0 = sb * per; if (t0 >= ntiles) t0 = ntiles - 1;
        recA = ((const f32x4*)rec)[(size_t)(t0 * 128 + wid * 16 + (lane & 15)) * 2 + rsub];
    }

    for (int it = 0; it < per; ++it) {
        const int tile = sb * per + it;
        if (tile >= ntiles) break;

        float px, py, pz, dxv, dyv, dzv;
        int pv;
        if constexpr (SORTED) {
            px  = __shfl(recA[0], c) * 127.0f;
            py  = __shfl(recA[1], c) * 127.0f;
            pz  = __shfl(recA[2], c) * 127.0f;
            dxv = __shfl(recA[3], c);
            dyv = __shfl(recA[0], 16 + c);
            dzv = __shfl(recA[1], 16 + c);
            pv  = __float_as_int(__shfl(recA[2], 16 + c));
        } else {
            int pw = tile * 128 + wid * 16;
            float cval = (lane < 48) ? coords[(size_t)pw * 3 + lane] : 0.0f;
            float rval = (lane < 48) ? ray_d[(size_t)pw * 3 + lane] : 0.0f;
            px  = __shfl(cval, 3 * c + 0) * 127.0f;
            py  = __shfl(cval, 3 * c + 1) * 127.0f;
            pz  = __shfl(cval, 3 * c + 2) * 127.0f;
            dxv = __shfl(rval, 3 * c + 0);
            dyv = __shfl(rval, 3 * c + 1);
            dzv = __shfl(rval, 3 * c + 2);
            pv  = pw + c;
        }
        int ix = (int)floorf(px); ix = ix < 0 ? 0 : (ix > 126 ? 126 : ix);
        int iy = (int)floorf(py); iy = iy < 0 ? 0 : (iy > 126 ? 126 : iy);
        int iz = (int)floorf(pz); iz = iz < 0 ? 0 : (iz > 126 ? 126 : iz);
        float tx = px - (float)ix;
        float ty = py - (float)iy;
        float tz = pz - (float)iz;

        f32x4 fa = {0.0f, 0.0f, 0.0f, 0.0f};
        f32x4 fb = {0.0f, 0.0f, 0.0f, 0.0f};
#pragma unroll
        for (int cc = 0; cc < 8; ++cc) {
            int ddx = (cc >> 2) & 1, ddy = (cc >> 1) & 1, ddz = cc & 1;
            float w = (ddx ? tx : 1.0f - tx) *
                      (ddy ? ty : 1.0f - ty) *
                      (ddz ? tz : 1.0f - tz);
            int idx = ((ix + ddx) << 14) + ((iy + ddy) << 7) + (iz + ddz);
            const f32x4* g = (const f32x4*)(grid + (size_t)idx * 32 + kg * 8);
            f32x4 v0 = g[0], v1 = g[1];
#pragma unroll
            for (int e = 0; e < 4; ++e) {
                fa[e] = fmaf(w, v0[e], fa[e]);
                fb[e] = fmaf(w, v1[e], fb[e]);
            }
        }
        BFU b0;
        b0.u[0] = pack2(fa[0], fa[1]); b0.u[1] = pack2(fa[2], fa[3]);
        b0.u[2] = pack2(fb[0], fb[1]); b0.u[3] = pack2(fb[2], fb[3]);

        f32x4 recB = recA;
        if constexpr (SORTED) {
            int tn = tile + 1; if (tn >= ntiles) tn = ntiles - 1;
            recB = ((const f32x4*)rec)[(size_t)(tn * 128 + wid * 16 + (lane & 15)) * 2 + rsub];
        }

        NERF_MLP_BODY(lds + 0)

        if (lane < 16) {
            f32x4 o;
            o[0] = 1.0f / (1.0f + __expf(-acco[0]));
            o[1] = 1.0f / (1.0f + __expf(-acco[1]));
            o[2] = 1.0f / (1.0f + __expf(-acco[2]));
            o[3] = dens;
            ((f32x4*)out)[pv] = o;
        }
        recA = recB;
    }
}

extern "C" void kernel_launch(void* const* d_in, const int* in_sizes, int n_in,
                              void* d_out, int out_size, void* d_ws, size_t ws_size,
                              hipStream_t stream) {
    const float* coords = (const float*)d_in[0];
    const float* ray_d  = (const float*)d_in[1];
    const float* grid   = (const float*)d_in[2];
    const float* wd1    = (const float*)d_in[3];
    const float* bd1    = (const float*)d_in[4];
    const float* wd2    = (const float*)d_in[5];
    const float* bd2    = (const float*)d_in[6];
    const float* wc1    = (const float*)d_in[7];
    const float* bc1    = (const float*)d_in[8];
    const float* wc2    = (const float*)d_in[9];
    const float* bc2    = (const float*)d_in[10];
    float* out = (float*)d_out;

    int N = in_sizes[0] / 3;
    int gridElems = in_sizes[2];
    int ntiles = N >> 7;

    char* ws = (char*)d_ws;
    __bf16* wp = (__bf16*)(ws + WS_WP);

    pack_weights<<<8, 256, 0, stream>>>(wd1, wd2, wc1, wc2, wp);

    int blocks = ntiles < 2048 ? ntiles : 2048;
    bool sortable = (N % (HB * 128)) == 0;

    if (ws_size >= WS_FULL && sortable) {
        unsigned int* mat   = (unsigned int*)(ws + WS_MAT);
        unsigned int* total = (unsigned int*)(ws + WS_TOT);
        unsigned int* bbase = (unsigned int*)(ws + WS_BB);
        float* rec = (float*)(ws + WS_REC);
        __bf16* gb = (__bf16*)(ws + WS_GB);
        int ppb = N / HB;
        int n8 = gridElems / 8;

        grid_to_bf16<<<(n8 + 255) / 256, 256, 0, stream>>>(grid, gb, n8);
        hist_lds<<<HB, 256, 0, stream>>>(coords, mat, ppb);
        col_scan<<<NBUCKET / 4, 256, 0, stream>>>(mat, total);
        bucket_scan<<<1, 256, 0, stream>>>(total, bbase);
        scatter_rec<<<HB, 256, 0, stream>>>(coords, ray_d, mat, bbase, rec, ppb);
        nerf_pipe<<<blocks, 512, 0, stream>>>(gb, rec,
                                              bd1, bd2, bc1, bc2, wp, out, ntiles);
    } else if (ws_size >= WS_R13 && sortable) {
        unsigned int* mat   = (unsigned int*)(ws + WS_MAT);
        unsigned int* total = (unsigned int*)(ws + WS_TOT);
        unsigned int* bbase = (unsigned int*)(ws + WS_BB);
        float* rec = (float*)(ws + WS_REC);
        int ppb = N / HB;

        hist_lds<<<HB, 256, 0, stream>>>(coords, mat, ppb);
        col_scan<<<NBUCKET / 4, 256, 0, stream>>>(mat, total);
        bucket_scan<<<1, 256, 0, stream>>>(total, bbase);
        scatter_rec<<<HB, 256, 0, stream>>>(coords, ray_d, mat, bbase, rec, ppb);
        nerf_wave<true><<<blocks, 512, 0, stream>>>(coords, ray_d, grid,
                                                    bd1, bd2, bc1, bc2,
                                                    wp, rec, out, ntiles);
    } else {
        nerf_wave<false><<<blocks, 512, 0, stream>>>(coords, ray_d, grid,
                                                     bd1, bd2, bc1, bc2,
                                                     wp, nullptr, out, ntiles);
    }
}

// Round 16
// 342.106 us; speedup vs baseline: 1.4870x; 1.0803x over previous
//
#include <hip/hip_runtime.h>
#include <hip/hip_bf16.h>
#include <math.h>

typedef __attribute__((ext_vector_type(8))) __bf16 bf16x8;
typedef __attribute__((ext_vector_type(4))) float f32x4;
typedef __attribute__((ext_vector_type(4))) int i32x4;

// ---- sort configuration ---------------------------------------------------
#define NBUCKET 512            // 8x8x8 regions of 16^3 cells
#define HB      256            // histogram blocks
// workspace layout (bytes)
#define WS_WP   0UL                    // packed weights     32 KB
#define WS_MAT  32768UL                // [HB][NBUCKET] u32  512 KB
#define WS_TOT  557056UL               // 512 u32
#define WS_BB   559104UL               // 512 u32
#define WS_REC  561152UL               // rec[N] 16 B        32 MB
#define WS_GB   34115584UL             // bf16 grid          134 MB
#define WS_FULL 168333312UL

// ---------------------------------------------------------------------------
// Pack MLP weights into MFMA A-fragment layout (weights-as-A).
//   frags 0-7: wd1 ident | 8-11: wd2 K-perm | 12-27: wc1 F-layout | 28-31: wc2
// K-perm row(kt,kg,j) = 32kt + 16(j>>2) + 4kg + (j&3): previous layer's
// D-layout is directly the next layer's B-fragment (zero cross-lane moves).
// ---------------------------------------------------------------------------
__global__ void pack_weights(const float* __restrict__ wd1,
                             const float* __restrict__ wd2,
                             const float* __restrict__ wc1,
                             const float* __restrict__ wc2,
                             __bf16* __restrict__ wp)
{
    int t = blockIdx.x * 256 + threadIdx.x;   // 8 blocks x 256 = 2048
    int frag = t >> 6;
    int lane = t & 63;
    int kg = lane >> 4;
    int c  = lane & 15;
    for (int j = 0; j < 8; ++j) {
        float v;
        if (frag < 8) {
            int k = kg * 8 + j;
            v = wd1[k * 128 + frag * 16 + c];
        } else if (frag < 12) {
            int kt = frag - 8;
            int row = 32 * kt + 16 * (j >> 2) + 4 * kg + (j & 3);
            v = wd2[row * 16 + c];
        } else if (frag < 28) {
            int f = frag - 12;
            int f3 = f >> 1, kt3 = f & 1;
            int row;
            if (kt3 == 0) row = (j < 4) ? (4 * kg + j) : (16 + 4 * kg + (j - 4));
            else          row = 32 + 8 * kg + j;
            v = (row < 43) ? wc1[row * 128 + f3 * 16 + c] : 0.0f;
        } else {
            int kt = frag - 28;
            int row = 32 * kt + 16 * (j >> 2) + 4 * kg + (j & 3);
            v = (c < 3) ? wc2[row * 3 + c] : 0.0f;
        }
        wp[frag * 512 + lane * 8 + j] = (__bf16)v;
    }
}

__device__ __forceinline__ int bucket_key(float x, float y, float z) {
    int ix = (int)(x * 127.0f); ix = ix < 0 ? 0 : (ix > 127 ? 127 : ix);
    int iy = (int)(y * 127.0f); iy = iy < 0 ? 0 : (iy > 127 ? 127 : iy);
    int iz = (int)(z * 127.0f); iz = iz < 0 ? 0 : (iz > 127 ? 127 : iz);
    return ((ix >> 4) << 6) | ((iy >> 4) << 3) | (iz >> 4);
}

// ---------------------------------------------------------------------------
// Fused: blocks [0,HB) build per-block histograms; blocks [HB,..) convert the
// fp32 grid to bf16. Independent work shares the memory pipe in one dispatch.
// ---------------------------------------------------------------------------
__global__ __launch_bounds__(256) void conv_hist(const float* __restrict__ g,
                                                 __bf16* __restrict__ gb,
                                                 int n8,
                                                 const float* __restrict__ coords,
                                                 unsigned int* __restrict__ mat,
                                                 int ppb)
{
    __shared__ unsigned int lh[NBUCKET];
    if (blockIdx.x < HB) {
        for (int i = threadIdx.x; i < NBUCKET; i += 256) lh[i] = 0u;
        __syncthreads();
        int base = blockIdx.x * ppb;
        for (int k = threadIdx.x; k < ppb; k += 256) {
            size_t b = 3 * (size_t)(base + k);
            atomicAdd(&lh[bucket_key(coords[b], coords[b + 1], coords[b + 2])], 1u);
        }
        __syncthreads();
        unsigned int* row = mat + (size_t)blockIdx.x * NBUCKET;
        for (int i = threadIdx.x; i < NBUCKET; i += 256) row[i] = lh[i];
    } else {
        int i0 = (blockIdx.x - HB) * 256 + threadIdx.x;
        int stride = (gridDim.x - HB) * 256;
        for (int i = i0; i < n8; i += stride) {
            const f32x4* p = (const f32x4*)g + 2 * (size_t)i;
            f32x4 a = p[0], b = p[1];
            bf16x8 o;
#pragma unroll
            for (int e = 0; e < 4; ++e) {
                o[e]     = (__bf16)a[e];
                o[4 + e] = (__bf16)b[e];
            }
            ((bf16x8*)gb)[i] = o;
        }
    }
}

__global__ __launch_bounds__(256) void col_scan(unsigned int* __restrict__ mat,
                                                unsigned int* __restrict__ total)
{
    int wid  = threadIdx.x >> 6;
    int lane = threadIdx.x & 63;
    int bkt  = blockIdx.x * 4 + wid;

    unsigned int v[4];
#pragma unroll
    for (int j = 0; j < 4; ++j)
        v[j] = mat[(size_t)(lane * 4 + j) * NBUCKET + bkt];
    unsigned int pre[4];
    unsigned int sum = 0;
#pragma unroll
    for (int j = 0; j < 4; ++j) { pre[j] = sum; sum += v[j]; }
    unsigned int inc = sum;
    for (int d = 1; d < 64; d <<= 1) {
        unsigned int u = __shfl_up(inc, d);
        if (lane >= d) inc += u;
    }
    unsigned int excl = inc - sum;
#pragma unroll
    for (int j = 0; j < 4; ++j)
        mat[(size_t)(lane * 4 + j) * NBUCKET + bkt] = excl + pre[j];
    if (lane == 63) total[bkt] = inc;
}

__global__ __launch_bounds__(256) void bucket_scan(const unsigned int* __restrict__ total,
                                                   unsigned int* __restrict__ bbase)
{
    int t = threadIdx.x;
    unsigned int v0 = total[2 * t], v1 = total[2 * t + 1];
    unsigned int run = v0 + v1;
    unsigned int lane = t & 63;
    int wid = t >> 6;
    unsigned int inc = run;
    for (int d = 1; d < 64; d <<= 1) {
        unsigned int u = __shfl_up(inc, d);
        if (lane >= (unsigned)d) inc += u;
    }
    __shared__ unsigned int wt[4];
    if (lane == 63) wt[wid] = inc;
    __syncthreads();
    unsigned int wbase = 0;
    for (int w = 0; w < wid; ++w) wbase += wt[w];
    unsigned int excl = wbase + inc - run;
    bbase[2 * t]     = excl;
    bbase[2 * t + 1] = excl + v0;
}

// ---------------------------------------------------------------------------
// Scatter packed 16-B records: {x,y,z as u16 fixed | dx,dy,dz as u16 | idx}.
// Quantization: coords err <= 7.6e-6 (t err ~1e-3 grid units), dirs 1.5e-5.
// ---------------------------------------------------------------------------
__device__ __forceinline__ unsigned int q16(float v01) {
    float v = v01 * 65535.0f + 0.5f;
    v = v < 0.0f ? 0.0f : (v > 65535.0f ? 65535.0f : v);
    return (unsigned int)v;
}

__global__ __launch_bounds__(256) void scatter_rec16(const float* __restrict__ coords,
                                                     const float* __restrict__ rayd,
                                                     const unsigned int* __restrict__ mat,
                                                     const unsigned int* __restrict__ bbase,
                                                     unsigned int* __restrict__ rec,
                                                     int ppb)
{
    __shared__ unsigned int cur[NBUCKET];
    const unsigned int* row = mat + (size_t)blockIdx.x * NBUCKET;
    for (int i = threadIdx.x; i < NBUCKET; i += 256)
        cur[i] = bbase[i] + row[i];
    __syncthreads();
    int base = blockIdx.x * ppb;
    for (int k = threadIdx.x; k < ppb; k += 256) {
        int i = base + k;
        size_t b = 3 * (size_t)i;
        float x = coords[b], y = coords[b + 1], z = coords[b + 2];
        unsigned int dst = atomicAdd(&cur[bucket_key(x, y, z)], 1u);
        unsigned int ux = q16(x), uy = q16(y), uz = q16(z);
        unsigned int vx = q16(fmaf(rayd[b],     0.5f, 0.5f));
        unsigned int vy = q16(fmaf(rayd[b + 1], 0.5f, 0.5f));
        unsigned int vz = q16(fmaf(rayd[b + 2], 0.5f, 0.5f));
        i32x4 r;
        r.x = (int)(ux | (uy << 16));
        r.y = (int)(uz | (vx << 16));
        r.z = (int)(vy | (vz << 16));
        r.w = i;
        ((i32x4*)rec)[dst] = r;
    }
}

__device__ __forceinline__ unsigned int pack2(float a, float b) {
    union { __bf16 h[2]; unsigned int u; } x;
    x.h[0] = (__bf16)a; x.h[1] = (__bf16)b;
    return x.u;
}

union BFU { bf16x8 v; unsigned int u[4]; };

// shared MLP body (L1->L4 given b0 frag + dirs dxv/dyv/dzv), LDSW = weight base
#define NERF_MLP_BODY(LDSW)                                                     \
    float s1x = __sinf(dxv), c1x = __cosf(dxv);                                 \
    float s1y = __sinf(dyv), c1y = __cosf(dyv);                                 \
    float s1z = __sinf(dzv), c1z = __cosf(dzv);                                 \
    float s2x = 2.0f * s1x * c1x, c2x = fmaf(-2.0f * s1x, s1x, 1.0f);           \
    float s2y = 2.0f * s1y * c1y, c2y = fmaf(-2.0f * s1y, s1y, 1.0f);           \
    float s2z = 2.0f * s1z * c1z, c2z = fmaf(-2.0f * s1z, s1z, 1.0f);           \
    float s4x = 2.0f * s2x * c2x, c4x = fmaf(-2.0f * s2x, s2x, 1.0f);           \
    float s4y = 2.0f * s2y * c2y, c4y = fmaf(-2.0f * s2y, s2y, 1.0f);           \
    float s4z = 2.0f * s2z * c2z, c4z = fmaf(-2.0f * s2z, s2z, 1.0f);           \
    float s8x = 2.0f * s4x * c4x, c8x = fmaf(-2.0f * s4x, s4x, 1.0f);           \
    float s8y = 2.0f * s4y * c4y, c8y = fmaf(-2.0f * s4y, s4y, 1.0f);           \
    float s8z = 2.0f * s4z * c4z, c8z = fmaf(-2.0f * s4z, s4z, 1.0f);           \
    float E0, E1, E2, E3, G0, G1, G2, G3, G4, G5, G6, G7;                       \
    if (kg == 0) {                                                              \
        E0 = dxv; E1 = dyv; E2 = dzv; E3 = s1x;                                 \
        G0 = c1y; G1 = c1z; G2 = c2x; G3 = c2y;                                 \
        G4 = c2z; G5 = c4x; G6 = c4y; G7 = c4z;                                 \
    } else if (kg == 1) {                                                       \
        E0 = s1y; E1 = s1z; E2 = s2x; E3 = s2y;                                 \
        G0 = c8x; G1 = c8y; G2 = c8z;                                           \
        G3 = 0.0f; G4 = 0.0f; G5 = 0.0f; G6 = 0.0f; G7 = 0.0f;                  \
    } else if (kg == 2) {                                                       \
        E0 = s2z; E1 = s4x; E2 = s4y; E3 = s4z;                                 \
        G0 = G1 = G2 = G3 = G4 = G5 = G6 = G7 = 0.0f;                           \
    } else {                                                                    \
        E0 = s8x; E1 = s8y; E2 = s8z; E3 = c1x;                                 \
        G0 = G1 = G2 = G3 = G4 = G5 = G6 = G7 = 0.0f;                           \
    }                                                                           \
    f32x4 acc[8];                                                               \
    _Pragma("unroll")                                                           \
    for (int n = 0; n < 8; ++n) {                                               \
        f32x4 bi = *(const f32x4*)(ldsB1 + n * 16 + kg * 4);                    \
        bf16x8 A = *(const bf16x8*)(LDSW + n * 1024 + lb);                      \
        acc[n] = __builtin_amdgcn_mfma_f32_16x16x32_bf16(A, b0.v, bi, 0, 0, 0); \
    }                                                                           \
    unsigned int pk[8][2];                                                      \
    _Pragma("unroll")                                                           \
    for (int n = 0; n < 8; ++n) {                                               \
        pk[n][0] = pack2(fmaxf(acc[n][0], 0.0f), fmaxf(acc[n][1], 0.0f));       \
        pk[n][1] = pack2(fmaxf(acc[n][2], 0.0f), fmaxf(acc[n][3], 0.0f));       \
    }                                                                           \
    f32x4 a2A = *(const f32x4*)(ldsB2 + kg * 4);                                \
    f32x4 a2B = {0.0f, 0.0f, 0.0f, 0.0f};                                       \
    _Pragma("unroll")                                                           \
    for (int kt = 0; kt < 4; ++kt) {                                            \
        BFU B;                                                                  \
        B.u[0] = pk[2 * kt][0];     B.u[1] = pk[2 * kt][1];                     \
        B.u[2] = pk[2 * kt + 1][0]; B.u[3] = pk[2 * kt + 1][1];                 \
        bf16x8 A = *(const bf16x8*)(LDSW + (8 + kt) * 1024 + lb);               \
        if (kt & 1) a2B = __builtin_amdgcn_mfma_f32_16x16x32_bf16(A, B.v, a2B, 0, 0, 0); \
        else        a2A = __builtin_amdgcn_mfma_f32_16x16x32_bf16(A, B.v, a2A, 0, 0, 0); \
    }                                                                           \
    f32x4 accd = a2A + a2B;                                                     \
    float dens = fmaxf(accd[0], 0.0f);                                          \
    BFU Bk0, Bk1;                                                               \
    Bk0.u[0] = pack2(accd[0], accd[1]);                                         \
    Bk0.u[1] = pack2(accd[2], accd[3]);                                         \
    Bk0.u[2] = pack2(E0, E1);                                                   \
    Bk0.u[3] = pack2(E2, E3);                                                   \
    Bk1.u[0] = pack2(G0, G1);                                                   \
    Bk1.u[1] = pack2(G2, G3);                                                   \
    Bk1.u[2] = pack2(G4, G5);                                                   \
    Bk1.u[3] = pack2(G6, G7);                                                   \
    f32x4 acc3[8];                                                              \
    _Pragma("unroll")                                                           \
    for (int n = 0; n < 8; ++n) {                                               \
        f32x4 bi = *(const f32x4*)(ldsB3 + n * 16 + kg * 4);                    \
        bf16x8 w0 = *(const bf16x8*)(LDSW + (12 + n * 2 + 0) * 1024 + lb);      \
        bf16x8 w1 = *(const bf16x8*)(LDSW + (12 + n * 2 + 1) * 1024 + lb);      \
        acc3[n] = __builtin_amdgcn_mfma_f32_16x16x32_bf16(w0, Bk0.v, bi, 0, 0, 0);      \
        acc3[n] = __builtin_amdgcn_mfma_f32_16x16x32_bf16(w1, Bk1.v, acc3[n], 0, 0, 0); \
    }                                                                           \
    unsigned int pk3[8][2];                                                     \
    _Pragma("unroll")                                                           \
    for (int n = 0; n < 8; ++n) {                                               \
        pk3[n][0] = pack2(fmaxf(acc3[n][0], 0.0f), fmaxf(acc3[n][1], 0.0f));    \
        pk3[n][1] = pack2(fmaxf(acc3[n][2], 0.0f), fmaxf(acc3[n][3], 0.0f));    \
    }                                                                           \
    f32x4 a4A = *(const f32x4*)(ldsB4 + kg * 4);                                \
    f32x4 a4B = {0.0f, 0.0f, 0.0f, 0.0f};                                       \
    _Pragma("unroll")                                                           \
    for (int kt = 0; kt < 4; ++kt) {                                            \
        BFU B;                                                                  \
        B.u[0] = pk3[2 * kt][0];     B.u[1] = pk3[2 * kt][1];                   \
        B.u[2] = pk3[2 * kt + 1][0]; B.u[3] = pk3[2 * kt + 1][1];               \
        bf16x8 A = *(const bf16x8*)(LDSW + (28 + kt) * 1024 + lb);              \
        if (kt & 1) a4B = __builtin_amdgcn_mfma_f32_16x16x32_bf16(A, B.v, a4B, 0, 0, 0); \
        else        a4A = __builtin_amdgcn_mfma_f32_16x16x32_bf16(A, B.v, a4A, 0, 0, 0); \
    }                                                                           \
    f32x4 acco = a4A + a4B;

// decode a 16-B record into point state (no cross-lane ops needed)
#define DECODE_REC(R)                                                            \
    float px  = (float)((unsigned)(R).x & 0xffffu) * (127.0f / 65535.0f);        \
    float py  = (float)((unsigned)(R).x >> 16)     * (127.0f / 65535.0f);        \
    float pz  = (float)((unsigned)(R).y & 0xffffu) * (127.0f / 65535.0f);        \
    float dxv = fmaf((float)((unsigned)(R).y >> 16),     2.0f / 65535.0f, -1.0f);\
    float dyv = fmaf((float)((unsigned)(R).z & 0xffffu), 2.0f / 65535.0f, -1.0f);\
    float dzv = fmaf((float)((unsigned)(R).z >> 16),     2.0f / 65535.0f, -1.0f);\
    int   pv  = (R).w;

// ---------------------------------------------------------------------------
// Pipelined main kernel: bf16 L3-resident grid; iteration t consumes corner
// slices loaded during t-1, issues t+1's 8 x 16-B corner loads, then runs the
// MLP while they fly. Each lane decodes its own point's 16-B record.
// ---------------------------------------------------------------------------
__global__ __launch_bounds__(512)
void nerf_pipe(const __bf16* __restrict__ gb,       // bf16 grid
               const unsigned int* __restrict__ rec,// sorted 16-B records
               const float* __restrict__ bd1,
               const float* __restrict__ bd2,
               const float* __restrict__ bc1,
               const float* __restrict__ bc2,
               const __bf16* __restrict__ wp,
               float* __restrict__ out,
               int ntiles)                          // 128-point tiles
{
    __shared__ __align__(16) char lds[32768 + 1152];
    float* ldsB1 = (float*)(lds + 32768);
    float* ldsB2 = ldsB1 + 128;
    float* ldsB3 = ldsB2 + 16;
    float* ldsB4 = ldsB3 + 128;

    const int tid = threadIdx.x;
    {
        const i32x4* src = (const i32x4*)wp;
        i32x4* dst = (i32x4*)lds;
        for (int i = tid; i < 2048; i += 512) dst[i] = src[i];
        if (tid < 128) ldsB1[tid] = bd1[tid];
        if (tid < 16)  ldsB2[tid] = bd2[tid];
        if (tid < 128) ldsB3[tid] = bc1[tid];
        if (tid < 16)  ldsB4[tid] = (tid < 3) ? bc2[tid] : 0.0f;
    }
    __syncthreads();

    const int lane = tid & 63;
    const int wid  = tid >> 6;
    const int c    = lane & 15;
    const int kg   = lane >> 4;
    const int lb   = lane * 16;

    const int per = (ntiles + gridDim.x - 1) / gridDim.x;
    int sb = blockIdx.x;
    if ((gridDim.x & 7) == 0)
        sb = (blockIdx.x & 7) * (gridDim.x >> 3) + (blockIdx.x >> 3);

    // ---- prologue ----------------------------------------------------------
    int t0 = sb * per;       if (t0 >= ntiles) t0 = ntiles - 1;
    int t1 = sb * per + 1;   if (t1 >= ntiles) t1 = ntiles - 1;
    i32x4 recA = ((const i32x4*)rec)[(size_t)t0 * 128 + wid * 16 + c];
    i32x4 recB = ((const i32x4*)rec)[(size_t)t1 * 128 + wid * 16 + c];

    bf16x8 g0, g1, g2, g3, g4, g5, g6, g7;
    float txc, tyc, tzc;
    {   // prep iter 0 from recA
        float px = (float)((unsigned)recA.x & 0xffffu) * (127.0f / 65535.0f);
        float py = (float)((unsigned)recA.x >> 16)     * (127.0f / 65535.0f);
        float pz = (float)((unsigned)recA.y & 0xffffu) * (127.0f / 65535.0f);
        int ix = (int)floorf(px); ix = ix < 0 ? 0 : (ix > 126 ? 126 : ix);
        int iy = (int)floorf(py); iy = iy < 0 ? 0 : (iy > 126 ? 126 : iy);
        int iz = (int)floorf(pz); iz = iz < 0 ? 0 : (iz > 126 ? 126 : iz);
        txc = px - (float)ix; tyc = py - (float)iy; tzc = pz - (float)iz;
        const __bf16* gp = gb + ((((size_t)ix << 14) + ((size_t)iy << 7) + iz) * 32 + kg * 8);
        g0 = *(const bf16x8*)(gp);
        g1 = *(const bf16x8*)(gp + 32);
        g2 = *(const bf16x8*)(gp + 4096);
        g3 = *(const bf16x8*)(gp + 4128);
        g4 = *(const bf16x8*)(gp + 524288);
        g5 = *(const bf16x8*)(gp + 524320);
        g6 = *(const bf16x8*)(gp + 528384);
        g7 = *(const bf16x8*)(gp + 528416);
    }

    for (int it = 0; it < per; ++it) {
        const int tile = sb * per + it;
        if (tile >= ntiles) break;

        // ---- consume current corner slices -> b0 frag ----------------------
        f32x4 fa = {0.0f, 0.0f, 0.0f, 0.0f};
        f32x4 fb = {0.0f, 0.0f, 0.0f, 0.0f};
        {
            const bf16x8 garr[8] = {g0, g1, g2, g3, g4, g5, g6, g7};
#pragma unroll
            for (int cc = 0; cc < 8; ++cc) {
                int ddx = (cc >> 2) & 1, ddy = (cc >> 1) & 1, ddz = cc & 1;
                float w = (ddx ? txc : 1.0f - txc) *
                          (ddy ? tyc : 1.0f - tyc) *
                          (ddz ? tzc : 1.0f - tzc);
                BFU g; g.v = garr[cc];   // load order == (dx,dy,dz) binary
                float l0 = __uint_as_float(g.u[0] << 16);
                float h0 = __uint_as_float(g.u[0] & 0xffff0000u);
                float l1 = __uint_as_float(g.u[1] << 16);
                float h1 = __uint_as_float(g.u[1] & 0xffff0000u);
                float l2 = __uint_as_float(g.u[2] << 16);
                float h2 = __uint_as_float(g.u[2] & 0xffff0000u);
                float l3 = __uint_as_float(g.u[3] << 16);
                float h3 = __uint_as_float(g.u[3] & 0xffff0000u);
                fa[0] = fmaf(w, l0, fa[0]); fa[1] = fmaf(w, h0, fa[1]);
                fa[2] = fmaf(w, l1, fa[2]); fa[3] = fmaf(w, h1, fa[3]);
                fb[0] = fmaf(w, l2, fb[0]); fb[1] = fmaf(w, h2, fb[1]);
                fb[2] = fmaf(w, l3, fb[2]); fb[3] = fmaf(w, h3, fb[3]);
            }
        }
        BFU b0;
        b0.u[0] = pack2(fa[0], fa[1]); b0.u[1] = pack2(fa[2], fa[3]);
        b0.u[2] = pack2(fb[0], fb[1]); b0.u[3] = pack2(fb[2], fb[3]);

        // ---- current dirs / output index (lane-local decode) ---------------
        float dxv = fmaf((float)((unsigned)recA.y >> 16),     2.0f / 65535.0f, -1.0f);
        float dyv = fmaf((float)((unsigned)recA.z & 0xffffu), 2.0f / 65535.0f, -1.0f);
        float dzv = fmaf((float)((unsigned)recA.z >> 16),     2.0f / 65535.0f, -1.0f);
        int   pv  = recA.w;

        // ---- prep NEXT iteration from recB: issue 8 corner loads -----------
        {
            float px = (float)((unsigned)recB.x & 0xffffu) * (127.0f / 65535.0f);
            float py = (float)((unsigned)recB.x >> 16)     * (127.0f / 65535.0f);
            float pz = (float)((unsigned)recB.y & 0xffffu) * (127.0f / 65535.0f);
            int ix = (int)floorf(px); ix = ix < 0 ? 0 : (ix > 126 ? 126 : ix);
            int iy = (int)floorf(py); iy = iy < 0 ? 0 : (iy > 126 ? 126 : iy);
            int iz = (int)floorf(pz); iz = iz < 0 ? 0 : (iz > 126 ? 126 : iz);
            txc = px - (float)ix; tyc = py - (float)iy; tzc = pz - (float)iz;
            const __bf16* gp = gb + ((((size_t)ix << 14) + ((size_t)iy << 7) + iz) * 32 + kg * 8);
            g0 = *(const bf16x8*)(gp);
            g1 = *(const bf16x8*)(gp + 32);
            g2 = *(const bf16x8*)(gp + 4096);
            g3 = *(const bf16x8*)(gp + 4128);
            g4 = *(const bf16x8*)(gp + 524288);
            g5 = *(const bf16x8*)(gp + 524320);
            g6 = *(const bf16x8*)(gp + 528384);
            g7 = *(const bf16x8*)(gp + 528416);
        }
        // rotate records: recA <- recB, load new recB (t+2)
        recA = recB;
        {
            int t2 = tile + 2; if (t2 >= ntiles) t2 = ntiles - 1;
            recB = ((const i32x4*)rec)[(size_t)t2 * 128 + wid * 16 + c];
        }

        // ---- MLP (corner loads above retire underneath) --------------------
        NERF_MLP_BODY(lds + 0)

        if (lane < 16) {
            f32x4 o;
            o[0] = 1.0f / (1.0f + __expf(-acco[0]));
            o[1] = 1.0f / (1.0f + __expf(-acco[1]));
            o[2] = 1.0f / (1.0f + __expf(-acco[2]));
            o[3] = dens;
            ((f32x4*)out)[pv] = o;
        }
    }
}

// ---------------------------------------------------------------------------
// Fallback (no workspace): unsorted fp32-gather kernel.
// ---------------------------------------------------------------------------
__global__ __launch_bounds__(512)
void nerf_plain(const float* __restrict__ coords,
                const float* __restrict__ ray_d,
                const float* __restrict__ grid,
                const float* __restrict__ bd1,
                const float* __restrict__ bd2,
                const float* __restrict__ bc1,
                const float* __restrict__ bc2,
                const __bf16* __restrict__ wp,
                float* __restrict__ out,
                int ntiles)
{
    __shared__ __align__(16) char lds[32768 + 1152];
    float* ldsB1 = (float*)(lds + 32768);
    float* ldsB2 = ldsB1 + 128;
    float* ldsB3 = ldsB2 + 16;
    float* ldsB4 = ldsB3 + 128;

    const int tid = threadIdx.x;
    {
        const i32x4* src = (const i32x4*)wp;
        i32x4* dst = (i32x4*)lds;
        for (int i = tid; i < 2048; i += 512) dst[i] = src[i];
        if (tid < 128) ldsB1[tid] = bd1[tid];
        if (tid < 16)  ldsB2[tid] = bd2[tid];
        if (tid < 128) ldsB3[tid] = bc1[tid];
        if (tid < 16)  ldsB4[tid] = (tid < 3) ? bc2[tid] : 0.0f;
    }
    __syncthreads();

    const int lane = tid & 63;
    const int wid  = tid >> 6;
    const int c    = lane & 15;
    const int kg   = lane >> 4;
    const int lb   = lane * 16;

    for (int tile = blockIdx.x; tile < ntiles; tile += gridDim.x) {
        int pw = tile * 128 + wid * 16;
        float cval = (lane < 48) ? coords[(size_t)pw * 3 + lane] : 0.0f;
        float rval = (lane < 48) ? ray_d[(size_t)pw * 3 + lane] : 0.0f;
        float px  = __shfl(cval, 3 * c + 0) * 127.0f;
        float py  = __shfl(cval, 3 * c + 1) * 127.0f;
        float pz  = __shfl(cval, 3 * c + 2) * 127.0f;
        float dxv = __shfl(rval, 3 * c + 0);
        float dyv = __shfl(rval, 3 * c + 1);
        float dzv = __shfl(rval, 3 * c + 2);
        int pv = pw + c;

        int ix = (int)floorf(px); ix = ix < 0 ? 0 : (ix > 126 ? 126 : ix);
        int iy = (int)floorf(py); iy = iy < 0 ? 0 : (iy > 126 ? 126 : iy);
        int iz = (int)floorf(pz); iz = iz < 0 ? 0 : (iz > 126 ? 126 : iz);
        float tx = px - (float)ix;
        float ty = py - (float)iy;
        float tz = pz - (float)iz;

        f32x4 fa = {0.0f, 0.0f, 0.0f, 0.0f};
        f32x4 fb = {0.0f, 0.0f, 0.0f, 0.0f};
#pragma unroll
        for (int cc = 0; cc < 8; ++cc) {
            int ddx = (cc >> 2) & 1, ddy = (cc >> 1) & 1, ddz = cc & 1;
            float w = (ddx ? tx : 1.0f - tx) *
                      (ddy ? ty : 1.0f - ty) *
                      (ddz ? tz : 1.0f - tz);
            int idx = ((ix + ddx) << 14) + ((iy + ddy) << 7) + (iz + ddz);
            const f32x4* g = (const f32x4*)(grid + (size_t)idx * 32 + kg * 8);
            f32x4 v0 = g[0], v1 = g[1];
#pragma unroll
            for (int e = 0; e < 4; ++e) {
                fa[e] = fmaf(w, v0[e], fa[e]);
                fb[e] = fmaf(w, v1[e], fb[e]);
            }
        }
        BFU b0;
        b0.u[0] = pack2(fa[0], fa[1]); b0.u[1] = pack2(fa[2], fa[3]);
        b0.u[2] = pack2(fb[0], fb[1]); b0.u[3] = pack2(fb[2], fb[3]);

        NERF_MLP_BODY(lds + 0)

        if (lane < 16) {
            f32x4 o;
            o[0] = 1.0f / (1.0f + __expf(-acco[0]));
            o[1] = 1.0f / (1.0f + __expf(-acco[1]));
            o[2] = 1.0f / (1.0f + __expf(-acco[2]));
            o[3] = dens;
            ((f32x4*)out)[pv] = o;
        }
    }
}

extern "C" void kernel_launch(void* const* d_in, const int* in_sizes, int n_in,
                              void* d_out, int out_size, void* d_ws, size_t ws_size,
                              hipStream_t stream) {
    const float* coords = (const float*)d_in[0];
    const float* ray_d  = (const float*)d_in[1];
    const float* grid   = (const float*)d_in[2];
    const float* wd1    = (const float*)d_in[3];
    const float* bd1    = (const float*)d_in[4];
    const float* wd2    = (const float*)d_in[5];
    const float* bd2    = (const float*)d_in[6];
    const float* wc1    = (const float*)d_in[7];
    const float* bc1    = (const float*)d_in[8];
    const float* wc2    = (const float*)d_in[9];
    const float* bc2    = (const float*)d_in[10];
    float* out = (float*)d_out;

    int N = in_sizes[0] / 3;
    int gridElems = in_sizes[2];
    int ntiles = N >> 7;

    char* ws = (char*)d_ws;
    __bf16* wp = (__bf16*)(ws + WS_WP);

    pack_weights<<<8, 256, 0, stream>>>(wd1, wd2, wc1, wc2, wp);

    bool sortable = (N % (HB * 128)) == 0;

    if (ws_size >= WS_FULL && sortable) {
        unsigned int* mat   = (unsigned int*)(ws + WS_MAT);
        unsigned int* total = (unsigned int*)(ws + WS_TOT);
        unsigned int* bbase = (unsigned int*)(ws + WS_BB);
        unsigned int* rec   = (unsigned int*)(ws + WS_REC);
        __bf16* gb = (__bf16*)(ws + WS_GB);
        int ppb = N / HB;
        int n8 = gridElems / 8;

        conv_hist<<<HB + 2048, 256, 0, stream>>>(grid, gb, n8, coords, mat, ppb);
        col_scan<<<NBUCKET / 4, 256, 0, stream>>>(mat, total);
        bucket_scan<<<1, 256, 0, stream>>>(total, bbase);
        scatter_rec16<<<HB, 256, 0, stream>>>(coords, ray_d, mat, bbase, rec, ppb);

        int blocks = ntiles < 1024 ? ntiles : 1024;
        nerf_pipe<<<blocks, 512, 0, stream>>>(gb, rec,
                                              bd1, bd2, bc1, bc2, wp, out, ntiles);
    } else {
        int blocks = ntiles < 2048 ? ntiles : 2048;
        nerf_plain<<<blocks, 512, 0, stream>>>(coords, ray_d, grid,
                                               bd1, bd2, bc1, bc2,
                                               wp, out, ntiles);
    }
}

// Round 17
// 331.048 us; speedup vs baseline: 1.5367x; 1.0334x over previous
//
#include <hip/hip_runtime.h>
#include <hip/hip_bf16.h>
#include <math.h>

typedef __attribute__((ext_vector_type(8))) __bf16 bf16x8;
typedef __attribute__((ext_vector_type(4))) float f32x4;
typedef __attribute__((ext_vector_type(4))) int i32x4;

// ---- sort configuration ---------------------------------------------------
#define NBUCKET 512            // 8x8x8 regions of 16^3 cells
#define HB      256            // histogram blocks
// workspace layout (bytes)
#define WS_WP   0UL                    // packed weights     32 KB
#define WS_MAT  32768UL                // [HB][NBUCKET] u32  512 KB
#define WS_TOT  557056UL               // 512 u32
#define WS_REC  561152UL               // rec[N] 16 B        32 MB
#define WS_GB   34115584UL             // bf16 grid          134 MB
#define WS_FULL 168333312UL

__device__ __forceinline__ int bucket_key(float x, float y, float z) {
    int ix = (int)(x * 127.0f); ix = ix < 0 ? 0 : (ix > 127 ? 127 : ix);
    int iy = (int)(y * 127.0f); iy = iy < 0 ? 0 : (iy > 127 ? 127 : iy);
    int iz = (int)(z * 127.0f); iz = iz < 0 ? 0 : (iz > 127 ? 127 : iz);
    return ((ix >> 4) << 6) | ((iy >> 4) << 3) | (iz >> 4);
}

// ---------------------------------------------------------------------------
// Dispatch 1: blocks 0-7 pack MLP weights into MFMA A-fragment layout;
// blocks 8..8+HB-1 build per-block LDS histograms.
//   frags 0-7: wd1 ident | 8-11: wd2 K-perm | 12-27: wc1 F-layout | 28-31: wc2
// K-perm row(kt,kg,j) = 32kt + 16(j>>2) + 4kg + (j&3): previous layer's
// D-layout is directly the next layer's B-fragment (zero cross-lane moves).
// ---------------------------------------------------------------------------
__global__ __launch_bounds__(256)
void pack_hist(const float* __restrict__ wd1,
               const float* __restrict__ wd2,
               const float* __restrict__ wc1,
               const float* __restrict__ wc2,
               __bf16* __restrict__ wp,
               const float* __restrict__ coords,
               unsigned int* __restrict__ mat,
               int ppb)
{
    __shared__ unsigned int lh[NBUCKET];
    if (blockIdx.x < 8) {
        int t = blockIdx.x * 256 + threadIdx.x;   // 0..2047
        int frag = t >> 6;
        int lane = t & 63;
        int kg = lane >> 4;
        int c  = lane & 15;
        for (int j = 0; j < 8; ++j) {
            float v;
            if (frag < 8) {
                int k = kg * 8 + j;
                v = wd1[k * 128 + frag * 16 + c];
            } else if (frag < 12) {
                int kt = frag - 8;
                int row = 32 * kt + 16 * (j >> 2) + 4 * kg + (j & 3);
                v = wd2[row * 16 + c];
            } else if (frag < 28) {
                int f = frag - 12;
                int f3 = f >> 1, kt3 = f & 1;
                int row;
                if (kt3 == 0) row = (j < 4) ? (4 * kg + j) : (16 + 4 * kg + (j - 4));
                else          row = 32 + 8 * kg + j;
                v = (row < 43) ? wc1[row * 128 + f3 * 16 + c] : 0.0f;
            } else {
                int kt = frag - 28;
                int row = 32 * kt + 16 * (j >> 2) + 4 * kg + (j & 3);
                v = (c < 3) ? wc2[row * 3 + c] : 0.0f;
            }
            wp[frag * 512 + lane * 8 + j] = (__bf16)v;
        }
    } else {
        int hb = blockIdx.x - 8;
        for (int i = threadIdx.x; i < NBUCKET; i += 256) lh[i] = 0u;
        __syncthreads();
        int base = hb * ppb;
        for (int k = threadIdx.x; k < ppb; k += 256) {
            size_t b = 3 * (size_t)(base + k);
            atomicAdd(&lh[bucket_key(coords[b], coords[b + 1], coords[b + 2])], 1u);
        }
        __syncthreads();
        unsigned int* row = mat + (size_t)hb * NBUCKET;
        for (int i = threadIdx.x; i < NBUCKET; i += 256) row[i] = lh[i];
    }
}

// ---------------------------------------------------------------------------
// Dispatch 2: per-bucket exclusive scan over HB blocks (in place) + totals.
// ---------------------------------------------------------------------------
__global__ __launch_bounds__(256) void col_scan(unsigned int* __restrict__ mat,
                                                unsigned int* __restrict__ total)
{
    int wid  = threadIdx.x >> 6;
    int lane = threadIdx.x & 63;
    int bkt  = blockIdx.x * 4 + wid;

    unsigned int v[4];
#pragma unroll
    for (int j = 0; j < 4; ++j)
        v[j] = mat[(size_t)(lane * 4 + j) * NBUCKET + bkt];
    unsigned int pre[4];
    unsigned int sum = 0;
#pragma unroll
    for (int j = 0; j < 4; ++j) { pre[j] = sum; sum += v[j]; }
    unsigned int inc = sum;
    for (int d = 1; d < 64; d <<= 1) {
        unsigned int u = __shfl_up(inc, d);
        if (lane >= d) inc += u;
    }
    unsigned int excl = inc - sum;
#pragma unroll
    for (int j = 0; j < 4; ++j)
        mat[(size_t)(lane * 4 + j) * NBUCKET + bkt] = excl + pre[j];
    if (lane == 63) total[bkt] = inc;
}

// ---------------------------------------------------------------------------
// Dispatch 3: blocks 0..HB-1 scatter packed 16-B records (with the 512-entry
// bucket-base scan inlined in the prologue); blocks >= HB convert the fp32
// grid to bf16 (overlaps the scatter on the memory pipe).
// Record: {x,y,z u16 | dx,dy,dz u16 | idx}. Coord quant err 7.6e-6.
// ---------------------------------------------------------------------------
__device__ __forceinline__ unsigned int q16(float v01) {
    float v = v01 * 65535.0f + 0.5f;
    v = v < 0.0f ? 0.0f : (v > 65535.0f ? 65535.0f : v);
    return (unsigned int)v;
}

__global__ __launch_bounds__(256)
void scatter_conv(const float* __restrict__ coords,
                  const float* __restrict__ rayd,
                  const unsigned int* __restrict__ mat,
                  const unsigned int* __restrict__ total,
                  unsigned int* __restrict__ rec,
                  int ppb,
                  const float* __restrict__ g,
                  __bf16* __restrict__ gb,
                  int n8)
{
    __shared__ unsigned int cur[NBUCKET];
    __shared__ unsigned int wt[4];
    if (blockIdx.x >= HB) {
        // ---- grid conversion ----
        int i0 = (blockIdx.x - HB) * 256 + threadIdx.x;
        int stride = (gridDim.x - HB) * 256;
        for (int i = i0; i < n8; i += stride) {
            const f32x4* p = (const f32x4*)g + 2 * (size_t)i;
            f32x4 a = p[0], b = p[1];
            bf16x8 o;
#pragma unroll
            for (int e = 0; e < 4; ++e) {
                o[e]     = (__bf16)a[e];
                o[4 + e] = (__bf16)b[e];
            }
            ((bf16x8*)gb)[i] = o;
        }
        return;
    }
    // ---- inline bucket-base scan (each block redundantly) ----
    {
        int t = threadIdx.x;
        unsigned int v0 = total[2 * t], v1 = total[2 * t + 1];
        unsigned int run = v0 + v1;
        unsigned int lane = t & 63;
        int wid = t >> 6;
        unsigned int inc = run;
        for (int d = 1; d < 64; d <<= 1) {
            unsigned int u = __shfl_up(inc, d);
            if (lane >= (unsigned)d) inc += u;
        }
        if (lane == 63) wt[wid] = inc;
        __syncthreads();
        unsigned int wbase = 0;
        for (int w = 0; w < wid; ++w) wbase += wt[w];
        unsigned int excl = wbase + inc - run;
        const unsigned int* row = mat + (size_t)blockIdx.x * NBUCKET;
        cur[2 * t]     = excl + row[2 * t];
        cur[2 * t + 1] = excl + v0 + row[2 * t + 1];
    }
    __syncthreads();
    int base = blockIdx.x * ppb;
    for (int k = threadIdx.x; k < ppb; k += 256) {
        int i = base + k;
        size_t b = 3 * (size_t)i;
        float x = coords[b], y = coords[b + 1], z = coords[b + 2];
        unsigned int dst = atomicAdd(&cur[bucket_key(x, y, z)], 1u);
        unsigned int ux = q16(x), uy = q16(y), uz = q16(z);
        unsigned int vx = q16(fmaf(rayd[b],     0.5f, 0.5f));
        unsigned int vy = q16(fmaf(rayd[b + 1], 0.5f, 0.5f));
        unsigned int vz = q16(fmaf(rayd[b + 2], 0.5f, 0.5f));
        i32x4 r;
        r.x = (int)(ux | (uy << 16));
        r.y = (int)(uz | (vx << 16));
        r.z = (int)(vy | (vz << 16));
        r.w = i;
        ((i32x4*)rec)[dst] = r;
    }
}

__device__ __forceinline__ unsigned int pack2(float a, float b) {
    union { __bf16 h[2]; unsigned int u; } x;
    x.h[0] = (__bf16)a; x.h[1] = (__bf16)b;
    return x.u;
}

union BFU { bf16x8 v; unsigned int u[4]; };

// shared MLP body (L1->L4 given b0 frag + dirs dxv/dyv/dzv), LDSW = weight base
#define NERF_MLP_BODY(LDSW)                                                     \
    float s1x = __sinf(dxv), c1x = __cosf(dxv);                                 \
    float s1y = __sinf(dyv), c1y = __cosf(dyv);                                 \
    float s1z = __sinf(dzv), c1z = __cosf(dzv);                                 \
    float s2x = 2.0f * s1x * c1x, c2x = fmaf(-2.0f * s1x, s1x, 1.0f);           \
    float s2y = 2.0f * s1y * c1y, c2y = fmaf(-2.0f * s1y, s1y, 1.0f);           \
    float s2z = 2.0f * s1z * c1z, c2z = fmaf(-2.0f * s1z, s1z, 1.0f);           \
    float s4x = 2.0f * s2x * c2x, c4x = fmaf(-2.0f * s2x, s2x, 1.0f);           \
    float s4y = 2.0f * s2y * c2y, c4y = fmaf(-2.0f * s2y, s2y, 1.0f);           \
    float s4z = 2.0f * s2z * c2z, c4z = fmaf(-2.0f * s2z, s2z, 1.0f);           \
    float s8x = 2.0f * s4x * c4x, c8x = fmaf(-2.0f * s4x, s4x, 1.0f);           \
    float s8y = 2.0f * s4y * c4y, c8y = fmaf(-2.0f * s4y, s4y, 1.0f);           \
    float s8z = 2.0f * s4z * c4z, c8z = fmaf(-2.0f * s4z, s4z, 1.0f);           \
    float E0, E1, E2, E3, G0, G1, G2, G3, G4, G5, G6, G7;                       \
    if (kg == 0) {                                                              \
        E0 = dxv; E1 = dyv; E2 = dzv; E3 = s1x;                                 \
        G0 = c1y; G1 = c1z; G2 = c2x; G3 = c2y;                                 \
        G4 = c2z; G5 = c4x; G6 = c4y; G7 = c4z;                                 \
    } else if (kg == 1) {                                                       \
        E0 = s1y; E1 = s1z; E2 = s2x; E3 = s2y;                                 \
        G0 = c8x; G1 = c8y; G2 = c8z;                                           \
        G3 = 0.0f; G4 = 0.0f; G5 = 0.0f; G6 = 0.0f; G7 = 0.0f;                  \
    } else if (kg == 2) {                                                       \
        E0 = s2z; E1 = s4x; E2 = s4y; E3 = s4z;                                 \
        G0 = G1 = G2 = G3 = G4 = G5 = G6 = G7 = 0.0f;                           \
    } else {                                                                    \
        E0 = s8x; E1 = s8y; E2 = s8z; E3 = c1x;                                 \
        G0 = G1 = G2 = G3 = G4 = G5 = G6 = G7 = 0.0f;                           \
    }                                                                           \
    f32x4 acc[8];                                                               \
    _Pragma("unroll")                                                           \
    for (int n = 0; n < 8; ++n) {                                               \
        f32x4 bi = *(const f32x4*)(ldsB1 + n * 16 + kg * 4);                    \
        bf16x8 A = *(const bf16x8*)(LDSW + n * 1024 + lb);                      \
        acc[n] = __builtin_amdgcn_mfma_f32_16x16x32_bf16(A, b0.v, bi, 0, 0, 0); \
    }                                                                           \
    unsigned int pk[8][2];                                                      \
    _Pragma("unroll")                                                           \
    for (int n = 0; n < 8; ++n) {                                               \
        pk[n][0] = pack2(fmaxf(acc[n][0], 0.0f), fmaxf(acc[n][1], 0.0f));       \
        pk[n][1] = pack2(fmaxf(acc[n][2], 0.0f), fmaxf(acc[n][3], 0.0f));       \
    }                                                                           \
    f32x4 a2A = *(const f32x4*)(ldsB2 + kg * 4);                                \
    f32x4 a2B = {0.0f, 0.0f, 0.0f, 0.0f};                                       \
    _Pragma("unroll")                                                           \
    for (int kt = 0; kt < 4; ++kt) {                                            \
        BFU B;                                                                  \
        B.u[0] = pk[2 * kt][0];     B.u[1] = pk[2 * kt][1];                     \
        B.u[2] = pk[2 * kt + 1][0]; B.u[3] = pk[2 * kt + 1][1];                 \
        bf16x8 A = *(const bf16x8*)(LDSW + (8 + kt) * 1024 + lb);               \
        if (kt & 1) a2B = __builtin_amdgcn_mfma_f32_16x16x32_bf16(A, B.v, a2B, 0, 0, 0); \
        else        a2A = __builtin_amdgcn_mfma_f32_16x16x32_bf16(A, B.v, a2A, 0, 0, 0); \
    }                                                                           \
    f32x4 accd = a2A + a2B;                                                     \
    float dens = fmaxf(accd[0], 0.0f);                                          \
    BFU Bk0, Bk1;                                                               \
    Bk0.u[0] = pack2(accd[0], accd[1]);                                         \
    Bk0.u[1] = pack2(accd[2], accd[3]);                                         \
    Bk0.u[2] = pack2(E0, E1);                                                   \
    Bk0.u[3] = pack2(E2, E3);                                                   \
    Bk1.u[0] = pack2(G0, G1);                                                   \
    Bk1.u[1] = pack2(G2, G3);                                                   \
    Bk1.u[2] = pack2(G4, G5);                                                   \
    Bk1.u[3] = pack2(G6, G7);                                                   \
    f32x4 acc3[8];                                                              \
    _Pragma("unroll")                                                           \
    for (int n = 0; n < 8; ++n) {                                               \
        f32x4 bi = *(const f32x4*)(ldsB3 + n * 16 + kg * 4);                    \
        bf16x8 w0 = *(const bf16x8*)(LDSW + (12 + n * 2 + 0) * 1024 + lb);      \
        bf16x8 w1 = *(const bf16x8*)(LDSW + (12 + n * 2 + 1) * 1024 + lb);      \
        acc3[n] = __builtin_amdgcn_mfma_f32_16x16x32_bf16(w0, Bk0.v, bi, 0, 0, 0);      \
        acc3[n] = __builtin_amdgcn_mfma_f32_16x16x32_bf16(w1, Bk1.v, acc3[n], 0, 0, 0); \
    }                                                                           \
    unsigned int pk3[8][2];                                                     \
    _Pragma("unroll")                                                           \
    for (int n = 0; n < 8; ++n) {                                               \
        pk3[n][0] = pack2(fmaxf(acc3[n][0], 0.0f), fmaxf(acc3[n][1], 0.0f));    \
        pk3[n][1] = pack2(fmaxf(acc3[n][2], 0.0f), fmaxf(acc3[n][3], 0.0f));    \
    }                                                                           \
    f32x4 a4A = *(const f32x4*)(ldsB4 + kg * 4);                                \
    f32x4 a4B = {0.0f, 0.0f, 0.0f, 0.0f};                                       \
    _Pragma("unroll")                                                           \
    for (int kt = 0; kt < 4; ++kt) {                                            \
        BFU B;                                                                  \
        B.u[0] = pk3[2 * kt][0];     B.u[1] = pk3[2 * kt][1];                   \
        B.u[2] = pk3[2 * kt + 1][0]; B.u[3] = pk3[2 * kt + 1][1];               \
        bf16x8 A = *(const bf16x8*)(LDSW + (28 + kt) * 1024 + lb);              \
        if (kt & 1) a4B = __builtin_amdgcn_mfma_f32_16x16x32_bf16(A, B.v, a4B, 0, 0, 0); \
        else        a4A = __builtin_amdgcn_mfma_f32_16x16x32_bf16(A, B.v, a4A, 0, 0, 0); \
    }                                                                           \
    f32x4 acco = a4A + a4B;

// consume one corner slice (bf16x8 -> 8 f32 fma into fa/fb)
#define CONSUME(GV, W) {                                                        \
    BFU g; g.v = (GV);                                                          \
    float w_ = (W);                                                             \
    fa[0] = fmaf(w_, __uint_as_float(g.u[0] << 16),          fa[0]);            \
    fa[1] = fmaf(w_, __uint_as_float(g.u[0] & 0xffff0000u),  fa[1]);            \
    fa[2] = fmaf(w_, __uint_as_float(g.u[1] << 16),          fa[2]);            \
    fa[3] = fmaf(w_, __uint_as_float(g.u[1] & 0xffff0000u),  fa[3]);            \
    fb[0] = fmaf(w_, __uint_as_float(g.u[2] << 16),          fb[0]);            \
    fb[1] = fmaf(w_, __uint_as_float(g.u[2] & 0xffff0000u),  fb[1]);            \
    fb[2] = fmaf(w_, __uint_as_float(g.u[3] << 16),          fb[2]);            \
    fb[3] = fmaf(w_, __uint_as_float(g.u[3] & 0xffff0000u),  fb[3]);            \
}

// ---------------------------------------------------------------------------
// Dispatch 4: pipelined main kernel. bf16 L3-resident grid; iteration t
// consumes corner slices loaded during t-1, issues t+1's 8 x 16-B loads,
// then runs the MLP while they fly. Lane-local 16-B record decode.
// ---------------------------------------------------------------------------
__global__ __launch_bounds__(512)
void nerf_pipe(const __bf16* __restrict__ gb,
               const unsigned int* __restrict__ rec,
               const float* __restrict__ bd1,
               const float* __restrict__ bd2,
               const float* __restrict__ bc1,
               const float* __restrict__ bc2,
               const __bf16* __restrict__ wp,
               float* __restrict__ out,
               int ntiles)                          // 128-point tiles
{
    __shared__ __align__(16) char lds[32768 + 1152];
    float* ldsB1 = (float*)(lds + 32768);
    float* ldsB2 = ldsB1 + 128;
    float* ldsB3 = ldsB2 + 16;
    float* ldsB4 = ldsB3 + 128;

    const int tid = threadIdx.x;
    {
        const i32x4* src = (const i32x4*)wp;
        i32x4* dst = (i32x4*)lds;
        for (int i = tid; i < 2048; i += 512) dst[i] = src[i];
        if (tid < 128) ldsB1[tid] = bd1[tid];
        if (tid < 16)  ldsB2[tid] = bd2[tid];
        if (tid < 128) ldsB3[tid] = bc1[tid];
        if (tid < 16)  ldsB4[tid] = (tid < 3) ? bc2[tid] : 0.0f;
    }
    __syncthreads();

    const int lane = tid & 63;
    const int wid  = tid >> 6;
    const int c    = lane & 15;
    const int kg   = lane >> 4;
    const int lb   = lane * 16;

    const int per = (ntiles + gridDim.x - 1) / gridDim.x;
    int sb = blockIdx.x;
    if ((gridDim.x & 7) == 0)
        sb = (blockIdx.x & 7) * (gridDim.x >> 3) + (blockIdx.x >> 3);

    // ---- prologue ----------------------------------------------------------
    int t0 = sb * per;       if (t0 >= ntiles) t0 = ntiles - 1;
    int t1 = sb * per + 1;   if (t1 >= ntiles) t1 = ntiles - 1;
    i32x4 recA = ((const i32x4*)rec)[(size_t)t0 * 128 + wid * 16 + c];
    i32x4 recB = ((const i32x4*)rec)[(size_t)t1 * 128 + wid * 16 + c];

    bf16x8 g0, g1, g2, g3, g4, g5, g6, g7;
    float txc, tyc, tzc;
    {   // prep iter 0 from recA
        float px = (float)((unsigned)recA.x & 0xffffu) * (127.0f / 65535.0f);
        float py = (float)((unsigned)recA.x >> 16)     * (127.0f / 65535.0f);
        float pz = (float)((unsigned)recA.y & 0xffffu) * (127.0f / 65535.0f);
        int ix = (int)floorf(px); ix = ix < 0 ? 0 : (ix > 126 ? 126 : ix);
        int iy = (int)floorf(py); iy = iy < 0 ? 0 : (iy > 126 ? 126 : iy);
        int iz = (int)floorf(pz); iz = iz < 0 ? 0 : (iz > 126 ? 126 : iz);
        txc = px - (float)ix; tyc = py - (float)iy; tzc = pz - (float)iz;
        const __bf16* gp = gb + ((((size_t)ix << 14) + ((size_t)iy << 7) + iz) * 32 + kg * 8);
        g0 = *(const bf16x8*)(gp);
        g1 = *(const bf16x8*)(gp + 32);
        g2 = *(const bf16x8*)(gp + 4096);
        g3 = *(const bf16x8*)(gp + 4128);
        g4 = *(const bf16x8*)(gp + 524288);
        g5 = *(const bf16x8*)(gp + 524320);
        g6 = *(const bf16x8*)(gp + 528384);
        g7 = *(const bf16x8*)(gp + 528416);
    }

    for (int it = 0; it < per; ++it) {
        const int tile = sb * per + it;
        if (tile >= ntiles) break;

        // ---- consume current corner slices -> b0 frag ----------------------
        f32x4 fa = {0.0f, 0.0f, 0.0f, 0.0f};
        f32x4 fb = {0.0f, 0.0f, 0.0f, 0.0f};
        {
            float wx1 = txc, wx0 = 1.0f - txc;
            float wy1 = tyc, wy0 = 1.0f - tyc;
            float wz1 = tzc, wz0 = 1.0f - tzc;
            float wA = wx0 * wy0, wB = wx0 * wy1;
            float wC = wx1 * wy0, wD = wx1 * wy1;
            CONSUME(g0, wA * wz0)   // (0,0,0)
            CONSUME(g1, wA * wz1)   // (0,0,1)
            CONSUME(g2, wB * wz0)   // (0,1,0)
            CONSUME(g3, wB * wz1)   // (0,1,1)
            CONSUME(g4, wC * wz0)   // (1,0,0)
            CONSUME(g5, wC * wz1)   // (1,0,1)
            CONSUME(g6, wD * wz0)   // (1,1,0)
            CONSUME(g7, wD * wz1)   // (1,1,1)
        }
        BFU b0;
        b0.u[0] = pack2(fa[0], fa[1]); b0.u[1] = pack2(fa[2], fa[3]);
        b0.u[2] = pack2(fb[0], fb[1]); b0.u[3] = pack2(fb[2], fb[3]);

        // ---- current dirs / output index (lane-local decode) ---------------
        float dxv = fmaf((float)((unsigned)recA.y >> 16),     2.0f / 65535.0f, -1.0f);
        float dyv = fmaf((float)((unsigned)recA.z & 0xffffu), 2.0f / 65535.0f, -1.0f);
        float dzv = fmaf((float)((unsigned)recA.z >> 16),     2.0f / 65535.0f, -1.0f);
        int   pv  = recA.w;

        // ---- prep NEXT iteration from recB: issue 8 corner loads -----------
        {
            float px = (float)((unsigned)recB.x & 0xffffu) * (127.0f / 65535.0f);
            float py = (float)((unsigned)recB.x >> 16)     * (127.0f / 65535.0f);
            float pz = (float)((unsigned)recB.y & 0xffffu) * (127.0f / 65535.0f);
            int ix = (int)floorf(px); ix = ix < 0 ? 0 : (ix > 126 ? 126 : ix);
            int iy = (int)floorf(py); iy = iy < 0 ? 0 : (iy > 126 ? 126 : iy);
            int iz = (int)floorf(pz); iz = iz < 0 ? 0 : (iz > 126 ? 126 : iz);
            txc = px - (float)ix; tyc = py - (float)iy; tzc = pz - (float)iz;
            const __bf16* gp = gb + ((((size_t)ix << 14) + ((size_t)iy << 7) + iz) * 32 + kg * 8);
            g0 = *(const bf16x8*)(gp);
            g1 = *(const bf16x8*)(gp + 32);
            g2 = *(const bf16x8*)(gp + 4096);
            g3 = *(const bf16x8*)(gp + 4128);
            g4 = *(const bf16x8*)(gp + 524288);
            g5 = *(const bf16x8*)(gp + 524320);
            g6 = *(const bf16x8*)(gp + 528384);
            g7 = *(const bf16x8*)(gp + 528416);
        }
        // rotate records: recA <- recB, load new recB (t+2)
        recA = recB;
        {
            int t2 = tile + 2; if (t2 >= ntiles) t2 = ntiles - 1;
            recB = ((const i32x4*)rec)[(size_t)t2 * 128 + wid * 16 + c];
        }

        // ---- MLP (corner loads above retire underneath) --------------------
        NERF_MLP_BODY(lds + 0)

        if (lane < 16) {
            f32x4 o;
            o[0] = 1.0f / (1.0f + __expf(-acco[0]));
            o[1] = 1.0f / (1.0f + __expf(-acco[1]));
            o[2] = 1.0f / (1.0f + __expf(-acco[2]));
            o[3] = dens;
            ((f32x4*)out)[pv] = o;
        }
    }
}

// ---------------------------------------------------------------------------
// Fallback (no workspace): unsorted fp32-gather kernel.
// ---------------------------------------------------------------------------
__global__ void pack_weights_fb(const float* __restrict__ wd1,
                                const float* __restrict__ wd2,
                                const float* __restrict__ wc1,
                                const float* __restrict__ wc2,
                                __bf16* __restrict__ wp)
{
    int t = blockIdx.x * 256 + threadIdx.x;
    int frag = t >> 6;
    int lane = t & 63;
    int kg = lane >> 4;
    int c  = lane & 15;
    for (int j = 0; j < 8; ++j) {
        float v;
        if (frag < 8) {
            int k = kg * 8 + j;
            v = wd1[k * 128 + frag * 16 + c];
        } else if (frag < 12) {
            int kt = frag - 8;
            int row = 32 * kt + 16 * (j >> 2) + 4 * kg + (j & 3);
            v = wd2[row * 16 + c];
        } else if (frag < 28) {
            int f = frag - 12;
            int f3 = f >> 1, kt3 = f & 1;
            int row;
            if (kt3 == 0) row = (j < 4) ? (4 * kg + j) : (16 + 4 * kg + (j - 4));
            else          row = 32 + 8 * kg + j;
            v = (row < 43) ? wc1[row * 128 + f3 * 16 + c] : 0.0f;
        } else {
            int kt = frag - 28;
            int row = 32 * kt + 16 * (j >> 2) + 4 * kg + (j & 3);
            v = (c < 3) ? wc2[row * 3 + c] : 0.0f;
        }
        wp[frag * 512 + lane * 8 + j] = (__bf16)v;
    }
}

__global__ __launch_bounds__(512)
void nerf_plain(const float* __restrict__ coords,
                const float* __restrict__ ray_d,
                const float* __restrict__ grid,
                const float* __restrict__ bd1,
                const float* __restrict__ bd2,
                const float* __restrict__ bc1,
                const float* __restrict__ bc2,
                const __bf16* __restrict__ wp,
                float* __restrict__ out,
                int ntiles)
{
    __shared__ __align__(16) char lds[32768 + 1152];
    float* ldsB1 = (float*)(lds + 32768);
    float* ldsB2 = ldsB1 + 128;
    float* ldsB3 = ldsB2 + 16;
    float* ldsB4 = ldsB3 + 128;

    const int tid = threadIdx.x;
    {
        const i32x4* src = (const i32x4*)wp;
        i32x4* dst = (i32x4*)lds;
        for (int i = tid; i < 2048; i += 512) dst[i] = src[i];
        if (tid < 128) ldsB1[tid] = bd1[tid];
        if (tid < 16)  ldsB2[tid] = bd2[tid];
        if (tid < 128) ldsB3[tid] = bc1[tid];
        if (tid < 16)  ldsB4[tid] = (tid < 3) ? bc2[tid] : 0.0f;
    }
    __syncthreads();

    const int lane = tid & 63;
    const int wid  = tid >> 6;
    const int c    = lane & 15;
    const int kg   = lane >> 4;
    const int lb   = lane * 16;

    for (int tile = blockIdx.x; tile < ntiles; tile += gridDim.x) {
        int pw = tile * 128 + wid * 16;
        float cval = (lane < 48) ? coords[(size_t)pw * 3 + lane] : 0.0f;
        float rval = (lane < 48) ? ray_d[(size_t)pw * 3 + lane] : 0.0f;
        float px  = __shfl(cval, 3 * c + 0) * 127.0f;
        float py  = __shfl(cval, 3 * c + 1) * 127.0f;
        float pz  = __shfl(cval, 3 * c + 2) * 127.0f;
        float dxv = __shfl(rval, 3 * c + 0);
        float dyv = __shfl(rval, 3 * c + 1);
        float dzv = __shfl(rval, 3 * c + 2);
        int pv = pw + c;

        int ix = (int)floorf(px); ix = ix < 0 ? 0 : (ix > 126 ? 126 : ix);
        int iy = (int)floorf(py); iy = iy < 0 ? 0 : (iy > 126 ? 126 : iy);
        int iz = (int)floorf(pz); iz = iz < 0 ? 0 : (iz > 126 ? 126 : iz);
        float tx = px - (float)ix;
        float ty = py - (float)iy;
        float tz = pz - (float)iz;

        f32x4 fa = {0.0f, 0.0f, 0.0f, 0.0f};
        f32x4 fb = {0.0f, 0.0f, 0.0f, 0.0f};
#pragma unroll
        for (int cc = 0; cc < 8; ++cc) {
            int ddx = (cc >> 2) & 1, ddy = (cc >> 1) & 1, ddz = cc & 1;
            float w = (ddx ? tx : 1.0f - tx) *
                      (ddy ? ty : 1.0f - ty) *
                      (ddz ? tz : 1.0f - tz);
            int idx = ((ix + ddx) << 14) + ((iy + ddy) << 7) + (iz + ddz);
            const f32x4* g = (const f32x4*)(grid + (size_t)idx * 32 + kg * 8);
            f32x4 v0 = g[0], v1 = g[1];
#pragma unroll
            for (int e = 0; e < 4; ++e) {
                fa[e] = fmaf(w, v0[e], fa[e]);
                fb[e] = fmaf(w, v1[e], fb[e]);
            }
        }
        BFU b0;
        b0.u[0] = pack2(fa[0], fa[1]); b0.u[1] = pack2(fa[2], fa[3]);
        b0.u[2] = pack2(fb[0], fb[1]); b0.u[3] = pack2(fb[2], fb[3]);

        NERF_MLP_BODY(lds + 0)

        if (lane < 16) {
            f32x4 o;
            o[0] = 1.0f / (1.0f + __expf(-acco[0]));
            o[1] = 1.0f / (1.0f + __expf(-acco[1]));
            o[2] = 1.0f / (1.0f + __expf(-acco[2]));
            o[3] = dens;
            ((f32x4*)out)[pv] = o;
        }
    }
}

extern "C" void kernel_launch(void* const* d_in, const int* in_sizes, int n_in,
                              void* d_out, int out_size, void* d_ws, size_t ws_size,
                              hipStream_t stream) {
    const float* coords = (const float*)d_in[0];
    const float* ray_d  = (const float*)d_in[1];
    const float* grid   = (const float*)d_in[2];
    const float* wd1    = (const float*)d_in[3];
    const float* bd1    = (const float*)d_in[4];
    const float* wd2    = (const float*)d_in[5];
    const float* bd2    = (const float*)d_in[6];
    const float* wc1    = (const float*)d_in[7];
    const float* bc1    = (const float*)d_in[8];
    const float* wc2    = (const float*)d_in[9];
    const float* bc2    = (const float*)d_in[10];
    float* out = (float*)d_out;

    int N = in_sizes[0] / 3;
    int gridElems = in_sizes[2];
    int ntiles = N >> 7;

    char* ws = (char*)d_ws;
    __bf16* wp = (__bf16*)(ws + WS_WP);

    bool sortable = (N % (HB * 128)) == 0;

    if (ws_size >= WS_FULL && sortable) {
        unsigned int* mat   = (unsigned int*)(ws + WS_MAT);
        unsigned int* total = (unsigned int*)(ws + WS_TOT);
        unsigned int* rec   = (unsigned int*)(ws + WS_REC);
        __bf16* gb = (__bf16*)(ws + WS_GB);
        int ppb = N / HB;
        int n8 = gridElems / 8;

        pack_hist<<<8 + HB, 256, 0, stream>>>(wd1, wd2, wc1, wc2, wp,
                                              coords, mat, ppb);
        col_scan<<<NBUCKET / 4, 256, 0, stream>>>(mat, total);
        scatter_conv<<<HB + 2048, 256, 0, stream>>>(coords, ray_d, mat, total,
                                                    rec, ppb, grid, gb, n8);
        int blocks = ntiles < 2048 ? ntiles : 2048;
        nerf_pipe<<<blocks, 512, 0, stream>>>(gb, rec,
                                              bd1, bd2, bc1, bc2, wp, out, ntiles);
    } else {
        pack_weights_fb<<<8, 256, 0, stream>>>(wd1, wd2, wc1, wc2, wp);
        int blocks = ntiles < 2048 ? ntiles : 2048;
        nerf_plain<<<blocks, 512, 0, stream>>>(coords, ray_d, grid,
                                               bd1, bd2, bc1, bc2,
                                               wp, out, ntiles);
    }
}